// Round 14
// baseline (1912.270 us; speedup 1.0000x reference)
//
#include <hip/hip_runtime.h>
#include <hip/hip_bf16.h>
#include <math.h>

#define BB 64
#define TT 256
#define LCH 16
#define DC 50
#define CHN 100
#define DW 300
#define DF 20
#define HID 256
#define G4 1024
#define INDIM 420
#define KPAD 448
#define NTAG 52
#define TSTART 50
#define TSTOP 51

// ------------------- workspace layout (bytes) -------------------
static constexpr size_t OFF_POOL  = 0;                       // 6,553,600 (dead after concat)
static constexpr size_t OFF_WH16F = 0;                       // 917,504 f16 (after concat)
static constexpr size_t OFF_WH16B = 917504;                  // -> 1,835,008
static constexpr size_t OFF_XH    = 6553600;                 // 14,680,064 f16 -> 21,233,664
static constexpr size_t OFF_HF    = 0;                       // 16,777,216 (lstm output)
static constexpr size_t OFF_HB    = 16777216;                // -> 33,554,432
static constexpr size_t OFF_XSF   = 34078720;                // 67,108,864
static constexpr size_t OFF_XSB   = 101187584;               // -> 168,296,448
static constexpr size_t OFF_FEATS = 168296448;               // 3,407,872 -> 171,704,320
static constexpr size_t OFF_WPF   = 171704320;               // 512 KB fp16 packed W_hh fwd
static constexpr size_t OFF_WPB   = 172752896;               // 512 KB fp16 packed W_hh bwd
static constexpr size_t OFF_LOSSB = 173801472;               // 256

typedef _Float16 v2h __attribute__((ext_vector_type(2)));
typedef _Float16 f16x8 __attribute__((ext_vector_type(8)));
typedef float f32x4 __attribute__((ext_vector_type(4)));
union UH2 { unsigned u; v2h h; };
__device__ __forceinline__ float fdot2u(unsigned a, unsigned b, float c) {
    UH2 x, y; x.u = a; y.u = b;
    return __builtin_amdgcn_fdot2(x.h, y.h, c, false);
}
__device__ __forceinline__ float dot8(uint4 w, uint4 h, float acc) {
    acc = fdot2u(w.x, h.x, acc);
    acc = fdot2u(w.y, h.y, acc);
    acc = fdot2u(w.z, h.z, acc);
    acc = fdot2u(w.w, h.w, acc);
    return acc;
}
#define KEEPU4(v) asm volatile("" : "+v"((v).x), "+v"((v).y), "+v"((v).z), "+v"((v).w))
// pin into AGPRs (unified file, separate allocator quota from the 64-VGPR wall)
#define KEEPA4(v) asm volatile("" : "+a"((v).x), "+a"((v).y), "+a"((v).z), "+a"((v).w))

__device__ __forceinline__ float sigm(float x) { return 1.0f / (1.0f + expf(-x)); }

// ---- fused prep: pack W_hh (both dirs) + cvt w_ih (both dirs)
__device__ __forceinline__ void packh_one(const float* __restrict__ w,
                                          _Float16* __restrict__ wph, int e) {
    int r  = e & 7;
    int j  = (e >> 3) & 255;
    int k8 = (e >> 11) & 7;
    int g  = (e >> 14) & 3;
    int s  = (e >> 16) & 3;
    wph[e] = (_Float16)w[(g * 256 + j) * HID + (s * 64 + k8 * 8 + r)];
}
__device__ __forceinline__ void cvtw_one(const float* __restrict__ w,
                                         _Float16* __restrict__ wh, int e) {
    int row = e / KPAD, k = e % KPAD;
    wh[e] = (k < INDIM) ? (_Float16)w[row * INDIM + k] : (_Float16)0.f;
}
__global__ void k_prep(const float* __restrict__ whf, const float* __restrict__ whb,
                       const float* __restrict__ wihf, const float* __restrict__ wihb,
                       _Float16* __restrict__ wpf, _Float16* __restrict__ wpb,
                       _Float16* __restrict__ wh16f, _Float16* __restrict__ wh16b) {
    int e = blockIdx.x * 256 + threadIdx.x;          // grid 5632 blocks
    if (e < 262144)                packh_one(whf, wpf, e);
    else if (e < 524288)           packh_one(whb, wpb, e - 262144);
    else if (e < 524288 + 458752)  cvtw_one(wihf, wh16f, e - 524288);
    else if (e < 524288 + 917504)  cvtw_one(wihb, wh16b, e - 983040);
}

// ---- char CNN: 8 words/block (2 concurrent x 4 iterations); conv weights in LDS
__global__ __launch_bounds__(256) void k_charcnn(const int* __restrict__ bchar,
                                                 const float* __restrict__ cemb,
                                                 const float* __restrict__ cw,
                                                 const float* __restrict__ cb,
                                                 float* __restrict__ pooled) {
    __shared__ float cwsh[150][100];   // [d*3+q][c], 60 KB
    __shared__ float ET[2][DC][20];
    __shared__ int ids[2][LCH];
    int tid = threadIdx.x;
    int wbase = blockIdx.x * 8;
    for (int i = tid; i < 15000; i += 256) {
        int row = i / 100, c = i % 100;
        cwsh[row][c] = cw[c * 150 + row];
    }
    int half = tid >> 7, c = tid & 127;
    float bcv = (c < CHN) ? cb[c] : 0.f;
    for (int g = 0; g < 8; g += 2) {
        __syncthreads();
        if (tid < 32) ids[tid >> 4][tid & 15] = bchar[(wbase + g + (tid >> 4)) * LCH + (tid & 15)];
        __syncthreads();
        for (int s2 = tid; s2 < 2 * DC * 18; s2 += 256) {
            int w2 = s2 / 900, rem = s2 % 900;
            int d = rem / 18, l = rem % 18;
            float v = 0.f;
            if (l >= 1 && l <= 16) v = cemb[ids[w2][l - 1] * DC + d];
            ET[w2][d][l] = v;
        }
        __syncthreads();
        if (c < CHN) {
            float acc[16];
#pragma unroll
            for (int l = 0; l < 16; l++) acc[l] = 0.f;
            for (int d = 0; d < DC; d++) {
                float e[18];
                float4 t0 = *(const float4*)&ET[half][d][0];
                float4 t1 = *(const float4*)&ET[half][d][4];
                float4 t2 = *(const float4*)&ET[half][d][8];
                float4 t3 = *(const float4*)&ET[half][d][12];
                e[0]=t0.x; e[1]=t0.y; e[2]=t0.z; e[3]=t0.w;
                e[4]=t1.x; e[5]=t1.y; e[6]=t1.z; e[7]=t1.w;
                e[8]=t2.x; e[9]=t2.y; e[10]=t2.z; e[11]=t2.w;
                e[12]=t3.x; e[13]=t3.y; e[14]=t3.z; e[15]=t3.w;
                e[16]=ET[half][d][16]; e[17]=ET[half][d][17];
                float w0 = cwsh[d * 3 + 0][c];
                float w1 = cwsh[d * 3 + 1][c];
                float w2 = cwsh[d * 3 + 2][c];
#pragma unroll
                for (int l = 0; l < 16; l++)
                    acc[l] += w0 * e[l] + w1 * e[l + 1] + w2 * e[l + 2];
            }
            float m = acc[0];
#pragma unroll
            for (int l = 1; l < 16; l++) m = fmaxf(m, acc[l]);
            pooled[(wbase + g + half) * CHN + c] = m + bcv;
        }
    }
}

// ---- assemble xh[16384][448] f16; 8 words per block (2048 blocks)
__global__ __launch_bounds__(128) void k_concat(const int* __restrict__ word,
                                                const int* __restrict__ featsidx,
                                                const int* __restrict__ recover,
                                                const float* __restrict__ wemb,
                                                const float* __restrict__ femb,
                                                const float* __restrict__ pooled,
                                                _Float16* __restrict__ xh) {
    int tid = threadIdx.x;
    for (int wi = 0; wi < 8; wi++) {
        int w = blockIdx.x * 8 + wi;
        int b = w >> 8;
        int wid = word[w];
        _Float16* xr = xh + (size_t)w * KPAD;
        for (int c = tid; c < DW; c += 128) xr[c] = (_Float16)wemb[(size_t)wid * DW + c];
        int rc = recover[w];
        if (tid < CHN) xr[DW + tid] = (_Float16)pooled[rc * CHN + tid];
        if (tid < DF)  xr[DW + CHN + tid] = (_Float16)femb[featsidx[b] * DF + tid];
        if (tid >= 100 && tid < 100 + (KPAD - INDIM)) xr[INDIM + (tid - 100)] = (_Float16)0.f;
    }
}

// ---- fused f16 MFMA GEMM for BOTH directions, LDS-staged (coalesced).
__global__ __launch_bounds__(256, 4) void k_gemm16b(const _Float16* __restrict__ A,
                                                    const _Float16* __restrict__ Bf,
                                                    const _Float16* __restrict__ Bb,
                                                    const float* __restrict__ biasf,
                                                    const float* __restrict__ biasb,
                                                    float* __restrict__ Cf,
                                                    float* __restrict__ Cb) {
    __shared__ __align__(16) _Float16 Asl[128 * 72];
    __shared__ __align__(16) _Float16 Bfl[64 * 72];
    __shared__ __align__(16) _Float16 Bbl[64 * 72];
    int tid = threadIdx.x;
    int wv = tid >> 6, l = tid & 63;
    int lm = l & 15, lk = l >> 4;
    int n0 = blockIdx.x * 64, m0 = blockIdx.y * 128;
    f32x4 z = {0.f, 0.f, 0.f, 0.f};
    f32x4 af0 = z, af1 = z, af2 = z, af3 = z;
    f32x4 ag0 = z, ag1 = z, ag2 = z, ag3 = z;
    f32x4 ab0 = z, ab1 = z, ab2 = z, ab3 = z;
    f32x4 ac0 = z, ac1 = z, ac2 = z, ac3 = z;
    for (int k0 = 0; k0 < KPAD; k0 += 64) {
        __syncthreads();
#pragma unroll
        for (int q = 0; q < 4; q++) {
            int ch = tid + q * 256;
            int r = ch >> 3, cc = ch & 7;
            ((uint4*)Asl)[r * 9 + cc] =
                *(const uint4*)&A[(size_t)(m0 + r) * KPAD + k0 + cc * 8];
        }
#pragma unroll
        for (int q = 0; q < 2; q++) {
            int ch = tid + q * 256;
            int r = ch >> 3, cc = ch & 7;
            ((uint4*)Bfl)[r * 9 + cc] =
                *(const uint4*)&Bf[(size_t)(n0 + r) * KPAD + k0 + cc * 8];
            ((uint4*)Bbl)[r * 9 + cc] =
                *(const uint4*)&Bb[(size_t)(n0 + r) * KPAD + k0 + cc * 8];
        }
        __syncthreads();
#pragma unroll
        for (int kstep = 0; kstep < 2; kstep++) {
            int kk = kstep * 4 + lk;
            f16x8 a0 = ((const f16x8*)Asl)[(wv * 32 + lm) * 9 + kk];
            f16x8 a1 = ((const f16x8*)Asl)[(wv * 32 + 16 + lm) * 9 + kk];
            f16x8 b0 = ((const f16x8*)Bfl)[(0 * 16 + lm) * 9 + kk];
            f16x8 b1 = ((const f16x8*)Bfl)[(1 * 16 + lm) * 9 + kk];
            f16x8 b2 = ((const f16x8*)Bfl)[(2 * 16 + lm) * 9 + kk];
            f16x8 b3 = ((const f16x8*)Bfl)[(3 * 16 + lm) * 9 + kk];
            f16x8 c0 = ((const f16x8*)Bbl)[(0 * 16 + lm) * 9 + kk];
            f16x8 c1 = ((const f16x8*)Bbl)[(1 * 16 + lm) * 9 + kk];
            f16x8 c2 = ((const f16x8*)Bbl)[(2 * 16 + lm) * 9 + kk];
            f16x8 c3 = ((const f16x8*)Bbl)[(3 * 16 + lm) * 9 + kk];
            af0 = __builtin_amdgcn_mfma_f32_16x16x32_f16(a0, b0, af0, 0, 0, 0);
            af1 = __builtin_amdgcn_mfma_f32_16x16x32_f16(a0, b1, af1, 0, 0, 0);
            af2 = __builtin_amdgcn_mfma_f32_16x16x32_f16(a0, b2, af2, 0, 0, 0);
            af3 = __builtin_amdgcn_mfma_f32_16x16x32_f16(a0, b3, af3, 0, 0, 0);
            ag0 = __builtin_amdgcn_mfma_f32_16x16x32_f16(a1, b0, ag0, 0, 0, 0);
            ag1 = __builtin_amdgcn_mfma_f32_16x16x32_f16(a1, b1, ag1, 0, 0, 0);
            ag2 = __builtin_amdgcn_mfma_f32_16x16x32_f16(a1, b2, ag2, 0, 0, 0);
            ag3 = __builtin_amdgcn_mfma_f32_16x16x32_f16(a1, b3, ag3, 0, 0, 0);
            ab0 = __builtin_amdgcn_mfma_f32_16x16x32_f16(a0, c0, ab0, 0, 0, 0);
            ab1 = __builtin_amdgcn_mfma_f32_16x16x32_f16(a0, c1, ab1, 0, 0, 0);
            ab2 = __builtin_amdgcn_mfma_f32_16x16x32_f16(a0, c2, ab2, 0, 0, 0);
            ab3 = __builtin_amdgcn_mfma_f32_16x16x32_f16(a0, c3, ab3, 0, 0, 0);
            ac0 = __builtin_amdgcn_mfma_f32_16x16x32_f16(a1, c0, ac0, 0, 0, 0);
            ac1 = __builtin_amdgcn_mfma_f32_16x16x32_f16(a1, c1, ac1, 0, 0, 0);
            ac2 = __builtin_amdgcn_mfma_f32_16x16x32_f16(a1, c2, ac2, 0, 0, 0);
            ac3 = __builtin_amdgcn_mfma_f32_16x16x32_f16(a1, c3, ac3, 0, 0, 0);
        }
    }
    f32x4 fa[2][4] = {{af0, af1, af2, af3}, {ag0, ag1, ag2, ag3}};
    f32x4 ba[2][4] = {{ab0, ab1, ab2, ab3}, {ac0, ac1, ac2, ac3}};
#pragma unroll
    for (int mi = 0; mi < 2; mi++) {
        int orow = m0 + wv * 32 + mi * 16 + lk * 4;
#pragma unroll
        for (int jn = 0; jn < 4; jn++) {
            int col = n0 + jn * 16 + lm;
            float bvf = biasf[col], bvb = biasb[col];
#pragma unroll
            for (int r = 0; r < 4; r++) {
                Cf[(size_t)(orow + r) * G4 + col] = fa[mi][jn][r] + bvf;
                Cb[(size_t)(orow + r) * G4 + col] = ba[mi][jn][r] + bvb;
            }
        }
    }
}

// ---- masked BiLSTM, ALL weights CU-resident:
//   i,f gates -> 64 AGPRs/thread ("+a" pins; unified file, separate quota
//   from the 64-VGPR allocator wall that blocked "+v" staging 4x),
//   g gate -> 32 VGPRs (proven resident at 60-reg usage),
//   o gate -> 128 KB LDS. Zero weight bytes streamed per step.
__global__ __launch_bounds__(1024, 4) void k_lstm(const float* __restrict__ xs_f,
                                               const float* __restrict__ xs_b,
                                               const _Float16* __restrict__ wh_f,
                                               const _Float16* __restrict__ wh_b,
                                               const int* __restrict__ wlen,
                                               float* __restrict__ h_f,
                                               float* __restrict__ h_b) {
    int b = blockIdx.x & 63, d = blockIdx.x >> 6;
    const float* xs = d ? xs_b : xs_f;
    const uint4* wp4 = (const uint4*)(d ? wh_b : wh_f);
    float* ho = d ? h_b : h_f;
    int len = wlen[b];
    __shared__ uint4 olds4[8192];                 // o-gate weights, 128 KB
    __shared__ _Float16 __align__(16) hh[256];    // f16 h state
    __shared__ float part[4][4][256];             // [s][gate][unit], 16 KB
    int tid = threadIdx.x;
    int j = tid & 255, s = tid >> 8;
    uint4 wi8[8], wf8[8];                          // i,f gates -> AGPRs
    uint4 wg[8];                                   // g gate -> VGPRs
    {
        const uint4* pi = wp4 + (size_t)((s * 4 + 0) * 8) * 256 + j;
        const uint4* pf = wp4 + (size_t)((s * 4 + 1) * 8) * 256 + j;
        const uint4* pg = wp4 + (size_t)((s * 4 + 2) * 8) * 256 + j;
        const uint4* po = wp4 + (size_t)((s * 4 + 3) * 8) * 256 + j;
#pragma unroll
        for (int k8 = 0; k8 < 8; k8++) {
            wi8[k8] = pi[k8 * 256];
            wf8[k8] = pf[k8 * 256];
            wg[k8] = pg[k8 * 256];
            olds4[k8 * 1024 + tid] = po[k8 * 256];
        }
    }
#pragma unroll
    for (int k8 = 0; k8 < 8; k8++) {
        KEEPA4(wi8[k8]);
        KEEPA4(wf8[k8]);
        KEEPU4(wg[k8]);
    }
    if (tid < 128) ((unsigned*)hh)[tid] = 0u;
    float c = 0.f;
    const uint4* hsh4 = (const uint4*)hh;
    __syncthreads();
    for (int ss = 0; ss < len; ++ss) {
        int t = d ? (len - 1 - ss) : ss;
        float xv0, xv1, xv2, xv3;
        if (tid < 256) {
            const float* xr = xs + (size_t)(b * TT + t) * G4;
            xv0 = xr[tid];
            xv1 = xr[256 + tid];
            xv2 = xr[512 + tid];
            xv3 = xr[768 + tid];
        }
        float a0 = 0.f, a1 = 0.f, a2 = 0.f, a3 = 0.f;
#pragma unroll
        for (int k8 = 0; k8 < 8; k8++) {
            uint4 h4 = hsh4[s * 8 + k8];                       // broadcast
            uint4 wo = olds4[k8 * 1024 + tid];
            a0 = dot8(wi8[k8], h4, a0);
            a1 = dot8(wf8[k8], h4, a1);
            a2 = dot8(wg[k8], h4, a2);
            a3 = dot8(wo, h4, a3);
        }
        part[s][0][j] = a0;
        part[s][1][j] = a1;
        part[s][2][j] = a2;
        part[s][3][j] = a3;
        __syncthreads();
        if (tid < 256) {
            float s0 = part[0][0][tid] + part[1][0][tid] + part[2][0][tid] + part[3][0][tid] + xv0;
            float s1 = part[0][1][tid] + part[1][1][tid] + part[2][1][tid] + part[3][1][tid] + xv1;
            float s2 = part[0][2][tid] + part[1][2][tid] + part[2][2][tid] + part[3][2][tid] + xv2;
            float s3 = part[0][3][tid] + part[1][3][tid] + part[2][3][tid] + part[3][3][tid] + xv3;
            float ig = sigm(s0), fg = sigm(s1), zg = tanhf(s2), og = sigm(s3);
            c = fg * c + ig * zg;
            float h = og * tanhf(c);
            hh[tid] = (_Float16)h;
            ho[(size_t)(b * TT + t) * HID + tid] = h;
        }
        __syncthreads();
    }
}

// ---- projection: proj_w LDS-resident (stride-513 pad), 64 words per block
__global__ __launch_bounds__(256) void k_proj(const float* __restrict__ hf,
                                              const float* __restrict__ hb,
                                              const float* __restrict__ pw,
                                              const float* __restrict__ pb,
                                              float* __restrict__ feats) {
    __shared__ float pwsh[NTAG][513];
    __shared__ float hsh[512];
    __shared__ float part2[4][NTAG];
    int tid = threadIdx.x;
    int w0 = blockIdx.x * 64;
    for (int i = tid; i < NTAG * 512; i += 256) pwsh[i >> 9][i & 511] = pw[i];
    __syncthreads();
    int q = tid >> 6, t = tid & 63;
    for (int wi = 0; wi < 64; wi++) {
        int w = w0 + wi;
        hsh[tid]       = hf[(size_t)w * HID + tid];
        hsh[256 + tid] = hb[(size_t)w * HID + tid];
        __syncthreads();
        if (t < NTAG) {
            float ssum = 0.f;
            int k0 = q * 128;
            for (int k = 0; k < 128; k++) ssum += pwsh[t][k0 + k] * hsh[k0 + k];
            part2[q][t] = ssum;
        }
        __syncthreads();
        if (tid < NTAG)
            feats[(size_t)w * NTAG + tid] =
                part2[0][tid] + part2[1][tid] + part2[2][tid] + part2[3][tid] + pb[tid];
        __syncthreads();
    }
}

// ---- CRF: 2 waves; wave0 = forward logsumexp (+parallel gold), wave1 = viterbi.
__global__ __launch_bounds__(128) void k_crf(const float* __restrict__ feats,
                                             const float* __restrict__ trans,
                                             const int* __restrict__ wlen,
                                             const int* __restrict__ blabel,
                                             float* __restrict__ lossb,
                                             float* __restrict__ outtags) {
    __shared__ float Tm[NTAG * NTAG];
    __shared__ float alpha[NTAG], valpha[NTAG], frow[NTAG], red[NTAG], red2[NTAG];
    __shared__ unsigned char bp[TT - 1][NTAG];
    int b = blockIdx.x;
    int tid = threadIdx.x;
    int j = tid & 63, wv = tid >> 6;
    for (int s = tid; s < NTAG * NTAG; s += 128) Tm[s] = trans[s];
    __syncthreads();
    int len = wlen[b];
    const float* fb = feats + (size_t)b * TT * NTAG;
    if (tid < NTAG) {
        float a = fb[tid] + Tm[TSTART * NTAG + tid];
        alpha[tid] = a;
        valpha[tid] = a;
    }
    __syncthreads();
    for (int t = 1; t < len; t++) {
        if (tid < NTAG) frow[tid] = fb[(size_t)t * NTAG + tid];
        __syncthreads();
        float anew = 0.f, vnew = 0.f;
        int arg = 0;
        if (wv == 0 && j < NTAG) {
            float ma = -1e30f, mb = -1e30f, mc = -1e30f, md = -1e30f;
            for (int i = 0; i < 13; i++) {
                ma = fmaxf(ma, alpha[i]      + Tm[i * NTAG + j]);
                mb = fmaxf(mb, alpha[i + 13] + Tm[(i + 13) * NTAG + j]);
                mc = fmaxf(mc, alpha[i + 26] + Tm[(i + 26) * NTAG + j]);
                md = fmaxf(md, alpha[i + 39] + Tm[(i + 39) * NTAG + j]);
            }
            float m1 = fmaxf(fmaxf(ma, mb), fmaxf(mc, md));
            float sa = 0.f, sb = 0.f, sc = 0.f, sd = 0.f;
            for (int i = 0; i < 13; i++) {
                sa += expf(alpha[i]      + Tm[i * NTAG + j] - m1);
                sb += expf(alpha[i + 13] + Tm[(i + 13) * NTAG + j] - m1);
                sc += expf(alpha[i + 26] + Tm[(i + 26) * NTAG + j] - m1);
                sd += expf(alpha[i + 39] + Tm[(i + 39) * NTAG + j] - m1);
            }
            anew = m1 + logf((sa + sb) + (sc + sd)) + frow[j];
        } else if (wv == 1 && j < NTAG) {
            float va = -1e30f, vb = -1e30f, vc = -1e30f, vd = -1e30f;
            int ia = 0, ib = 13, ic = 26, id2 = 39;
            for (int i = 0; i < 13; i++) {
                float s0 = valpha[i]      + Tm[i * NTAG + j];        if (s0 > va) { va = s0; ia = i; }
                float s1 = valpha[i + 13] + Tm[(i + 13) * NTAG + j]; if (s1 > vb) { vb = s1; ib = i + 13; }
                float s2 = valpha[i + 26] + Tm[(i + 26) * NTAG + j]; if (s2 > vc) { vc = s2; ic = i + 26; }
                float s3 = valpha[i + 39] + Tm[(i + 39) * NTAG + j]; if (s3 > vd) { vd = s3; id2 = i + 39; }
            }
            float vm = va; arg = ia;
            if (vb > vm) { vm = vb; arg = ib; }
            if (vc > vm) { vm = vc; arg = ic; }
            if (vd > vm) { vm = vd; arg = id2; }
            vnew = vm + frow[j];
        }
        __syncthreads();
        if (wv == 0 && j < NTAG) {
            alpha[j] = anew;
        } else if (wv == 1 && j < NTAG) {
            valpha[j] = vnew;
            bp[t - 1][j] = (unsigned char)arg;
        }
        __syncthreads();
    }
    if (tid < NTAG) {
        red[tid]  = alpha[tid] + Tm[tid * NTAG + TSTOP];
        red2[tid] = valpha[tid] + Tm[tid * NTAG + TSTOP];
    }
    __syncthreads();
    // wave0: parallel gold transition+emission sum over t=1..len-1
    float gpart = 0.f;
    if (wv == 0) {
        const int* lab = blabel + b * TT;
        for (int t = 1 + j; t < len; t += 64)
            gpart += Tm[lab[t - 1] * NTAG + lab[t]] + fb[(size_t)t * NTAG + lab[t]];
#pragma unroll
        for (int m = 32; m; m >>= 1) gpart += __shfl_xor(gpart, m);
    }
    if (tid == 0) {
        float m1 = red[0];
        for (int i = 1; i < NTAG; i++) m1 = fmaxf(m1, red[i]);
        float ssum = 0.f;
        for (int i = 0; i < NTAG; i++) ssum += expf(red[i] - m1);
        float Zg = m1 + logf(ssum);
        const int* lab = blabel + b * TT;
        float goldv = Tm[TSTART * NTAG + lab[0]] + fb[lab[0]] + gpart
                    + Tm[lab[len - 1] * NTAG + TSTOP];
        lossb[b] = Zg - goldv;
    } else if (tid == 64) {
        int best = 0;
        float vm = red2[0];
        for (int i = 1; i < NTAG; i++)
            if (red2[i] > vm) { vm = red2[i]; best = i; }
        float* ot = outtags + (size_t)b * TT;
        int tag = best;
        ot[len - 1] = (float)tag;
        for (int t = len - 2; t >= 0; t--) {
            tag = bp[t][tag];
            ot[t] = (float)tag;
        }
        for (int t = len; t < TT; t++) ot[t] = 0.f;
    }
}

// ---- deterministic final loss reduction
__global__ void k_loss(const float* __restrict__ lossb, float* __restrict__ out) {
    if (threadIdx.x == 0 && blockIdx.x == 0) {
        float s = 0.f;
        for (int i = 0; i < BB; i++) s += lossb[i];
        out[0] = s;
    }
}

extern "C" void kernel_launch(void* const* d_in, const int* in_sizes, int n_in,
                              void* d_out, int out_size, void* d_ws, size_t ws_size,
                              hipStream_t stream) {
    const int* batch_word     = (const int*)d_in[0];
    const int* batch_features = (const int*)d_in[1];
    const int* batch_wordlen  = (const int*)d_in[2];
    const int* batch_char     = (const int*)d_in[3];
    const int* batch_recover  = (const int*)d_in[5];
    const int* batch_label    = (const int*)d_in[7];
    const float* char_emb = (const float*)d_in[8];
    const float* conv_w   = (const float*)d_in[9];
    const float* conv_b   = (const float*)d_in[10];
    const float* word_emb = (const float*)d_in[11];
    const float* feat_emb = (const float*)d_in[12];
    const float* w_ih_f   = (const float*)d_in[13];
    const float* w_hh_f   = (const float*)d_in[14];
    const float* b_f      = (const float*)d_in[15];
    const float* w_ih_b   = (const float*)d_in[16];
    const float* w_hh_b   = (const float*)d_in[17];
    const float* b_b      = (const float*)d_in[18];
    const float* proj_w   = (const float*)d_in[19];
    const float* proj_b   = (const float*)d_in[20];
    const float* trans    = (const float*)d_in[21];

    char* ws = (char*)d_ws;
    float* pooled   = (float*)(ws + OFF_POOL);
    _Float16* wh16f = (_Float16*)(ws + OFF_WH16F);
    _Float16* wh16b = (_Float16*)(ws + OFF_WH16B);
    _Float16* xh    = (_Float16*)(ws + OFF_XH);
    float* h_f    = (float*)(ws + OFF_HF);
    float* h_b    = (float*)(ws + OFF_HB);
    float* xs_f   = (float*)(ws + OFF_XSF);
    float* xs_b   = (float*)(ws + OFF_XSB);
    float* feats  = (float*)(ws + OFF_FEATS);
    _Float16* wh_f = (_Float16*)(ws + OFF_WPF);
    _Float16* wh_b = (_Float16*)(ws + OFF_WPB);
    float* lossb  = (float*)(ws + OFF_LOSSB);

    k_charcnn<<<(BB * TT) / 8, 256, 0, stream>>>(batch_char, char_emb, conv_w, conv_b, pooled);
    k_concat<<<(BB * TT) / 8, 128, 0, stream>>>(batch_word, batch_features, batch_recover,
                                                word_emb, feat_emb, pooled, xh);
    // pooled dead now -> wh16 conversions may overwrite that region.
    k_prep<<<5632, 256, 0, stream>>>(w_hh_f, w_hh_b, w_ih_f, w_ih_b,
                                     wh_f, wh_b, wh16f, wh16b);
    k_gemm16b<<<dim3(G4 / 64, (BB * TT) / 128), 256, 0, stream>>>(xh, wh16f, wh16b,
                                                                  b_f, b_b, xs_f, xs_b);
    k_lstm<<<128, 1024, 0, stream>>>(xs_f, xs_b, wh_f, wh_b, batch_wordlen, h_f, h_b);
    k_proj<<<(BB * TT) / 64, 256, 0, stream>>>(h_f, h_b, proj_w, proj_b, feats);
    k_crf<<<BB, 128, 0, stream>>>(feats, trans, batch_wordlen, batch_label,
                                  lossb, (float*)d_out + 1);
    k_loss<<<1, 64, 0, stream>>>(lossb, (float*)d_out);
}

// Round 15
// 1700.788 us; speedup vs baseline: 1.1243x; 1.1243x over previous
//
#include <hip/hip_runtime.h>
#include <hip/hip_bf16.h>
#include <math.h>

#define BB 64
#define TT 256
#define LCH 16
#define DC 50
#define CHN 100
#define DW 300
#define DF 20
#define HID 256
#define G4 1024
#define INDIM 420
#define KPAD 448
#define NTAG 52
#define TSTART 50
#define TSTOP 51

// ------------------- workspace layout (bytes) -------------------
static constexpr size_t OFF_POOL  = 0;                       // 6,553,600 (dead after concat)
static constexpr size_t OFF_WH16F = 0;                       // unused early region alias
static constexpr size_t OFF_XH    = 6553600;                 // 14,680,064 f16 -> 21,233,664
static constexpr size_t OFF_W16F  = 21233664;                // 917,504 f16 w_ih fwd
static constexpr size_t OFF_W16B  = 22151168;                // -> 23,068,672
static constexpr size_t OFF_HF    = 0;                       // 16,777,216 (lstm output)
static constexpr size_t OFF_HB    = 16777216;                // -> 33,554,432
static constexpr size_t OFF_XSF   = 34078720;                // 67,108,864
static constexpr size_t OFF_XSB   = 101187584;               // -> 168,296,448
static constexpr size_t OFF_FEATS = 168296448;               // 3,407,872 -> 171,704,320
static constexpr size_t OFF_WPF   = 171704320;               // 512 KB fp16 packed W_hh fwd
static constexpr size_t OFF_WPB   = 172752896;               // 512 KB fp16 packed W_hh bwd
static constexpr size_t OFF_LOSSB = 173801472;               // 256 B (64 floats)
static constexpr size_t OFF_CTR   = 173801728;               // 4 B (unsigned counter)

typedef _Float16 v2h __attribute__((ext_vector_type(2)));
typedef _Float16 f16x8 __attribute__((ext_vector_type(8)));
typedef float f32x4 __attribute__((ext_vector_type(4)));
union UH2 { unsigned u; v2h h; };
__device__ __forceinline__ float fdot2u(unsigned a, unsigned b, float c) {
    UH2 x, y; x.u = a; y.u = b;
    return __builtin_amdgcn_fdot2(x.h, y.h, c, false);
}
__device__ __forceinline__ float dot8(uint4 w, uint4 h, float acc) {
    acc = fdot2u(w.x, h.x, acc);
    acc = fdot2u(w.y, h.y, acc);
    acc = fdot2u(w.z, h.z, acc);
    acc = fdot2u(w.w, h.w, acc);
    return acc;
}
#define KEEPU4(v) asm volatile("" : "+v"((v).x), "+v"((v).y), "+v"((v).z), "+v"((v).w))

__device__ __forceinline__ float sigm(float x) { return 1.0f / (1.0f + expf(-x)); }

// ================= fused front kernel: charcnn (blocks 0..2047) +
//                   prep pack/cvt (blocks 2048..7679) + counter zero ==========
#define CHARCNN_BLOCKS 2048
#define PREP_BLOCKS 5632

__device__ __forceinline__ void packh_one(const float* __restrict__ w,
                                          _Float16* __restrict__ wph, int e) {
    int r  = e & 7;
    int j  = (e >> 3) & 255;
    int k8 = (e >> 11) & 7;
    int g  = (e >> 14) & 3;
    int s  = (e >> 16) & 3;
    wph[e] = (_Float16)w[(g * 256 + j) * HID + (s * 64 + k8 * 8 + r)];
}
__device__ __forceinline__ void cvtw_one(const float* __restrict__ w,
                                         _Float16* __restrict__ wh, int e) {
    int row = e / KPAD, k = e % KPAD;
    wh[e] = (k < INDIM) ? (_Float16)w[row * INDIM + k] : (_Float16)0.f;
}

__global__ __launch_bounds__(256) void k_front(const int* __restrict__ bchar,
                                               const float* __restrict__ cemb,
                                               const float* __restrict__ cw,
                                               const float* __restrict__ cb,
                                               float* __restrict__ pooled,
                                               const float* __restrict__ whf,
                                               const float* __restrict__ whb,
                                               const float* __restrict__ wihf,
                                               const float* __restrict__ wihb,
                                               _Float16* __restrict__ wpf,
                                               _Float16* __restrict__ wpb,
                                               _Float16* __restrict__ wh16f,
                                               _Float16* __restrict__ wh16b,
                                               unsigned* __restrict__ ctr) {
    __shared__ float cwsh[150][100];   // [d*3+q][c], 60 KB
    __shared__ float ET[2][DC][20];
    __shared__ int ids[2][LCH];
    int tid = threadIdx.x;
    if (blockIdx.x >= CHARCNN_BLOCKS) {
        // ---- prep body ----
        int e = (blockIdx.x - CHARCNN_BLOCKS) * 256 + tid;
        if (e == 0) *ctr = 0u;                       // zero last-block counter
        if (e < 262144)                packh_one(whf, wpf, e);
        else if (e < 524288)           packh_one(whb, wpb, e - 262144);
        else if (e < 524288 + 458752)  cvtw_one(wihf, wh16f, e - 524288);
        else if (e < 524288 + 917504)  cvtw_one(wihb, wh16b, e - 983040);
        return;
    }
    // ---- charcnn body: 8 words/block ----
    int wbase = blockIdx.x * 8;
    for (int i = tid; i < 15000; i += 256) {
        int row = i / 100, c = i % 100;
        cwsh[row][c] = cw[c * 150 + row];
    }
    int half = tid >> 7, c = tid & 127;
    float bcv = (c < CHN) ? cb[c] : 0.f;
    for (int g = 0; g < 8; g += 2) {
        __syncthreads();
        if (tid < 32) ids[tid >> 4][tid & 15] = bchar[(wbase + g + (tid >> 4)) * LCH + (tid & 15)];
        __syncthreads();
        for (int s2 = tid; s2 < 2 * DC * 18; s2 += 256) {
            int w2 = s2 / 900, rem = s2 % 900;
            int d = rem / 18, l = rem % 18;
            float v = 0.f;
            if (l >= 1 && l <= 16) v = cemb[ids[w2][l - 1] * DC + d];
            ET[w2][d][l] = v;
        }
        __syncthreads();
        if (c < CHN) {
            float acc[16];
#pragma unroll
            for (int l = 0; l < 16; l++) acc[l] = 0.f;
            for (int d = 0; d < DC; d++) {
                float e[18];
                float4 t0 = *(const float4*)&ET[half][d][0];
                float4 t1 = *(const float4*)&ET[half][d][4];
                float4 t2 = *(const float4*)&ET[half][d][8];
                float4 t3 = *(const float4*)&ET[half][d][12];
                e[0]=t0.x; e[1]=t0.y; e[2]=t0.z; e[3]=t0.w;
                e[4]=t1.x; e[5]=t1.y; e[6]=t1.z; e[7]=t1.w;
                e[8]=t2.x; e[9]=t2.y; e[10]=t2.z; e[11]=t2.w;
                e[12]=t3.x; e[13]=t3.y; e[14]=t3.z; e[15]=t3.w;
                e[16]=ET[half][d][16]; e[17]=ET[half][d][17];
                float w0 = cwsh[d * 3 + 0][c];
                float w1 = cwsh[d * 3 + 1][c];
                float w2 = cwsh[d * 3 + 2][c];
#pragma unroll
                for (int l = 0; l < 16; l++)
                    acc[l] += w0 * e[l] + w1 * e[l + 1] + w2 * e[l + 2];
            }
            float m = acc[0];
#pragma unroll
            for (int l = 1; l < 16; l++) m = fmaxf(m, acc[l]);
            pooled[(wbase + g + half) * CHN + c] = m + bcv;
        }
    }
}

// ---- assemble xh[16384][448] f16; 8 words per block, 256 threads
__global__ __launch_bounds__(256) void k_concat(const int* __restrict__ word,
                                                const int* __restrict__ featsidx,
                                                const int* __restrict__ recover,
                                                const float* __restrict__ wemb,
                                                const float* __restrict__ femb,
                                                const float* __restrict__ pooled,
                                                _Float16* __restrict__ xh) {
    int tid = threadIdx.x;
    for (int wi = 0; wi < 8; wi++) {
        int w = blockIdx.x * 8 + wi;
        int b = w >> 8;
        int wid = word[w];
        _Float16* xr = xh + (size_t)w * KPAD;
        for (int c = tid; c < DW; c += 256) xr[c] = (_Float16)wemb[(size_t)wid * DW + c];
        int rc = recover[w];
        if (tid < CHN) xr[DW + tid] = (_Float16)pooled[rc * CHN + tid];
        if (tid < DF)  xr[DW + CHN + tid] = (_Float16)femb[featsidx[b] * DF + tid];
        if (tid >= 100 && tid < 100 + (KPAD - INDIM)) xr[INDIM + (tid - 100)] = (_Float16)0.f;
    }
}

// ---- fused f16 MFMA GEMM for BOTH directions, LDS-staged (coalesced).
__global__ __launch_bounds__(256, 4) void k_gemm16b(const _Float16* __restrict__ A,
                                                    const _Float16* __restrict__ Bf,
                                                    const _Float16* __restrict__ Bb,
                                                    const float* __restrict__ biasf,
                                                    const float* __restrict__ biasb,
                                                    float* __restrict__ Cf,
                                                    float* __restrict__ Cb) {
    __shared__ __align__(16) _Float16 Asl[128 * 72];
    __shared__ __align__(16) _Float16 Bfl[64 * 72];
    __shared__ __align__(16) _Float16 Bbl[64 * 72];
    int tid = threadIdx.x;
    int wv = tid >> 6, l = tid & 63;
    int lm = l & 15, lk = l >> 4;
    int n0 = blockIdx.x * 64, m0 = blockIdx.y * 128;
    f32x4 z = {0.f, 0.f, 0.f, 0.f};
    f32x4 af0 = z, af1 = z, af2 = z, af3 = z;
    f32x4 ag0 = z, ag1 = z, ag2 = z, ag3 = z;
    f32x4 ab0 = z, ab1 = z, ab2 = z, ab3 = z;
    f32x4 ac0 = z, ac1 = z, ac2 = z, ac3 = z;
    for (int k0 = 0; k0 < KPAD; k0 += 64) {
        __syncthreads();
#pragma unroll
        for (int q = 0; q < 4; q++) {
            int ch = tid + q * 256;
            int r = ch >> 3, cc = ch & 7;
            ((uint4*)Asl)[r * 9 + cc] =
                *(const uint4*)&A[(size_t)(m0 + r) * KPAD + k0 + cc * 8];
        }
#pragma unroll
        for (int q = 0; q < 2; q++) {
            int ch = tid + q * 256;
            int r = ch >> 3, cc = ch & 7;
            ((uint4*)Bfl)[r * 9 + cc] =
                *(const uint4*)&Bf[(size_t)(n0 + r) * KPAD + k0 + cc * 8];
            ((uint4*)Bbl)[r * 9 + cc] =
                *(const uint4*)&Bb[(size_t)(n0 + r) * KPAD + k0 + cc * 8];
        }
        __syncthreads();
#pragma unroll
        for (int kstep = 0; kstep < 2; kstep++) {
            int kk = kstep * 4 + lk;
            f16x8 a0 = ((const f16x8*)Asl)[(wv * 32 + lm) * 9 + kk];
            f16x8 a1 = ((const f16x8*)Asl)[(wv * 32 + 16 + lm) * 9 + kk];
            f16x8 b0 = ((const f16x8*)Bfl)[(0 * 16 + lm) * 9 + kk];
            f16x8 b1 = ((const f16x8*)Bfl)[(1 * 16 + lm) * 9 + kk];
            f16x8 b2 = ((const f16x8*)Bfl)[(2 * 16 + lm) * 9 + kk];
            f16x8 b3 = ((const f16x8*)Bfl)[(3 * 16 + lm) * 9 + kk];
            f16x8 c0 = ((const f16x8*)Bbl)[(0 * 16 + lm) * 9 + kk];
            f16x8 c1 = ((const f16x8*)Bbl)[(1 * 16 + lm) * 9 + kk];
            f16x8 c2 = ((const f16x8*)Bbl)[(2 * 16 + lm) * 9 + kk];
            f16x8 c3 = ((const f16x8*)Bbl)[(3 * 16 + lm) * 9 + kk];
            af0 = __builtin_amdgcn_mfma_f32_16x16x32_f16(a0, b0, af0, 0, 0, 0);
            af1 = __builtin_amdgcn_mfma_f32_16x16x32_f16(a0, b1, af1, 0, 0, 0);
            af2 = __builtin_amdgcn_mfma_f32_16x16x32_f16(a0, b2, af2, 0, 0, 0);
            af3 = __builtin_amdgcn_mfma_f32_16x16x32_f16(a0, b3, af3, 0, 0, 0);
            ag0 = __builtin_amdgcn_mfma_f32_16x16x32_f16(a1, b0, ag0, 0, 0, 0);
            ag1 = __builtin_amdgcn_mfma_f32_16x16x32_f16(a1, b1, ag1, 0, 0, 0);
            ag2 = __builtin_amdgcn_mfma_f32_16x16x32_f16(a1, b2, ag2, 0, 0, 0);
            ag3 = __builtin_amdgcn_mfma_f32_16x16x32_f16(a1, b3, ag3, 0, 0, 0);
            ab0 = __builtin_amdgcn_mfma_f32_16x16x32_f16(a0, c0, ab0, 0, 0, 0);
            ab1 = __builtin_amdgcn_mfma_f32_16x16x32_f16(a0, c1, ab1, 0, 0, 0);
            ab2 = __builtin_amdgcn_mfma_f32_16x16x32_f16(a0, c2, ab2, 0, 0, 0);
            ab3 = __builtin_amdgcn_mfma_f32_16x16x32_f16(a0, c3, ab3, 0, 0, 0);
            ac0 = __builtin_amdgcn_mfma_f32_16x16x32_f16(a1, c0, ac0, 0, 0, 0);
            ac1 = __builtin_amdgcn_mfma_f32_16x16x32_f16(a1, c1, ac1, 0, 0, 0);
            ac2 = __builtin_amdgcn_mfma_f32_16x16x32_f16(a1, c2, ac2, 0, 0, 0);
            ac3 = __builtin_amdgcn_mfma_f32_16x16x32_f16(a1, c3, ac3, 0, 0, 0);
        }
    }
    f32x4 fa[2][4] = {{af0, af1, af2, af3}, {ag0, ag1, ag2, ag3}};
    f32x4 ba[2][4] = {{ab0, ab1, ab2, ab3}, {ac0, ac1, ac2, ac3}};
#pragma unroll
    for (int mi = 0; mi < 2; mi++) {
        int orow = m0 + wv * 32 + mi * 16 + lk * 4;
#pragma unroll
        for (int jn = 0; jn < 4; jn++) {
            int col = n0 + jn * 16 + lm;
            float bvf = biasf[col], bvb = biasb[col];
#pragma unroll
            for (int r = 0; r < 4; r++) {
                Cf[(size_t)(orow + r) * G4 + col] = fa[mi][jn][r] + bvf;
                Cb[(size_t)(orow + r) * G4 + col] = ba[mi][jn][r] + bvb;
            }
        }
    }
}

// ---- masked BiLSTM (r13 EXACT revert): o-gate in 128 KB LDS; g-gate pinned
// in 32 VGPRs; i,f streamed 256 KB/step from L2 (per-CU L2-path floor).
__global__ __launch_bounds__(1024, 4) void k_lstm(const float* __restrict__ xs_f,
                                               const float* __restrict__ xs_b,
                                               const _Float16* __restrict__ wh_f,
                                               const _Float16* __restrict__ wh_b,
                                               const int* __restrict__ wlen,
                                               float* __restrict__ h_f,
                                               float* __restrict__ h_b) {
    int b = blockIdx.x & 63, d = blockIdx.x >> 6;
    const float* xs = d ? xs_b : xs_f;
    const uint4* wp4 = (const uint4*)(d ? wh_b : wh_f);
    float* ho = d ? h_b : h_f;
    int len = wlen[b];
    __shared__ uint4 olds4[8192];                 // o-gate weights, 128 KB
    __shared__ _Float16 __align__(16) hh[256];    // f16 h state
    __shared__ float part[4][4][256];             // [s][gate][unit], 16 KB
    int tid = threadIdx.x;
    int j = tid & 255, s = tid >> 8;
    const uint4* pi = wp4 + (size_t)((s * 4 + 0) * 8) * 256 + j;   // i (streamed)
    const uint4* pf = wp4 + (size_t)((s * 4 + 1) * 8) * 256 + j;   // f (streamed)
    uint4 wg[8];                                   // g-gate resident (32 VGPRs)
    {
        const uint4* pg = wp4 + (size_t)((s * 4 + 2) * 8) * 256 + j;
        const uint4* po = wp4 + (size_t)((s * 4 + 3) * 8) * 256 + j;
#pragma unroll
        for (int k8 = 0; k8 < 8; k8++) {
            wg[k8] = pg[k8 * 256];
            olds4[k8 * 1024 + tid] = po[k8 * 256];
        }
    }
#pragma unroll
    for (int k8 = 0; k8 < 8; k8++) KEEPU4(wg[k8]);
    if (tid < 128) ((unsigned*)hh)[tid] = 0u;
    float c = 0.f;
    const uint4* hsh4 = (const uint4*)hh;
    __syncthreads();
    for (int ss = 0; ss < len; ++ss) {
        int t = d ? (len - 1 - ss) : ss;
        float xv0, xv1, xv2, xv3;
        if (tid < 256) {
            const float* xr = xs + (size_t)(b * TT + t) * G4;
            xv0 = xr[tid];
            xv1 = xr[256 + tid];
            xv2 = xr[512 + tid];
            xv3 = xr[768 + tid];
        }
        asm volatile("" : "+v"(pi), "+v"(pf));
        float a0 = 0.f, a1 = 0.f, a2 = 0.f, a3 = 0.f;
#pragma unroll
        for (int k8 = 0; k8 < 8; k8++) {
            uint4 h4 = hsh4[s * 8 + k8];                       // broadcast
            uint4 wi = pi[k8 * 256];
            uint4 wf = pf[k8 * 256];
            uint4 wo = olds4[k8 * 1024 + tid];
            a0 = dot8(wi, h4, a0);
            a1 = dot8(wf, h4, a1);
            a2 = dot8(wg[k8], h4, a2);
            a3 = dot8(wo, h4, a3);
        }
        part[s][0][j] = a0;
        part[s][1][j] = a1;
        part[s][2][j] = a2;
        part[s][3][j] = a3;
        __syncthreads();
        if (tid < 256) {
            float s0 = part[0][0][tid] + part[1][0][tid] + part[2][0][tid] + part[3][0][tid] + xv0;
            float s1 = part[0][1][tid] + part[1][1][tid] + part[2][1][tid] + part[3][1][tid] + xv1;
            float s2 = part[0][2][tid] + part[1][2][tid] + part[2][2][tid] + part[3][2][tid] + xv2;
            float s3 = part[0][3][tid] + part[1][3][tid] + part[2][3][tid] + part[3][3][tid] + xv3;
            float ig = sigm(s0), fg = sigm(s1), zg = tanhf(s2), og = sigm(s3);
            c = fg * c + ig * zg;
            float h = og * tanhf(c);
            hh[tid] = (_Float16)h;
            ho[(size_t)(b * TT + t) * HID + tid] = h;
        }
        __syncthreads();
    }
}

// ---- projection: proj_w LDS-resident (stride-513 pad), 64 words per block
__global__ __launch_bounds__(256) void k_proj(const float* __restrict__ hf,
                                              const float* __restrict__ hb,
                                              const float* __restrict__ pw,
                                              const float* __restrict__ pb,
                                              float* __restrict__ feats) {
    __shared__ float pwsh[NTAG][513];
    __shared__ float hsh[512];
    __shared__ float part2[4][NTAG];
    int tid = threadIdx.x;
    int w0 = blockIdx.x * 64;
    for (int i = tid; i < NTAG * 512; i += 256) pwsh[i >> 9][i & 511] = pw[i];
    __syncthreads();
    int q = tid >> 6, t = tid & 63;
    for (int wi = 0; wi < 64; wi++) {
        int w = w0 + wi;
        hsh[tid]       = hf[(size_t)w * HID + tid];
        hsh[256 + tid] = hb[(size_t)w * HID + tid];
        __syncthreads();
        if (t < NTAG) {
            float ssum = 0.f;
            int k0 = q * 128;
            for (int k = 0; k < 128; k++) ssum += pwsh[t][k0 + k] * hsh[k0 + k];
            part2[q][t] = ssum;
        }
        __syncthreads();
        if (tid < NTAG)
            feats[(size_t)w * NTAG + tid] =
                part2[0][tid] + part2[1][tid] + part2[2][tid] + part2[3][tid] + pb[tid];
        __syncthreads();
    }
}

// ---- CRF: 2 waves; wave0 = forward logsumexp (+parallel gold), wave1 = viterbi.
// Last-finishing block also reduces lossb -> out[0] (counter zeroed by k_front;
// fixed-order sum by a single block => deterministic).
__global__ __launch_bounds__(128) void k_crf(const float* __restrict__ feats,
                                             const float* __restrict__ trans,
                                             const int* __restrict__ wlen,
                                             const int* __restrict__ blabel,
                                             float* __restrict__ lossb,
                                             float* __restrict__ outtags,
                                             unsigned* __restrict__ ctr,
                                             float* __restrict__ out) {
    __shared__ float Tm[NTAG * NTAG];
    __shared__ float alpha[NTAG], valpha[NTAG], frow[NTAG], red[NTAG], red2[NTAG];
    __shared__ unsigned char bp[TT - 1][NTAG];
    int b = blockIdx.x;
    int tid = threadIdx.x;
    int j = tid & 63, wv = tid >> 6;
    for (int s = tid; s < NTAG * NTAG; s += 128) Tm[s] = trans[s];
    __syncthreads();
    int len = wlen[b];
    const float* fb = feats + (size_t)b * TT * NTAG;
    if (tid < NTAG) {
        float a = fb[tid] + Tm[TSTART * NTAG + tid];
        alpha[tid] = a;
        valpha[tid] = a;
    }
    __syncthreads();
    for (int t = 1; t < len; t++) {
        if (tid < NTAG) frow[tid] = fb[(size_t)t * NTAG + tid];
        __syncthreads();
        float anew = 0.f, vnew = 0.f;
        int arg = 0;
        if (wv == 0 && j < NTAG) {
            float ma = -1e30f, mb = -1e30f, mc = -1e30f, md = -1e30f;
            for (int i = 0; i < 13; i++) {
                ma = fmaxf(ma, alpha[i]      + Tm[i * NTAG + j]);
                mb = fmaxf(mb, alpha[i + 13] + Tm[(i + 13) * NTAG + j]);
                mc = fmaxf(mc, alpha[i + 26] + Tm[(i + 26) * NTAG + j]);
                md = fmaxf(md, alpha[i + 39] + Tm[(i + 39) * NTAG + j]);
            }
            float m1 = fmaxf(fmaxf(ma, mb), fmaxf(mc, md));
            float sa = 0.f, sb = 0.f, sc = 0.f, sd = 0.f;
            for (int i = 0; i < 13; i++) {
                sa += expf(alpha[i]      + Tm[i * NTAG + j] - m1);
                sb += expf(alpha[i + 13] + Tm[(i + 13) * NTAG + j] - m1);
                sc += expf(alpha[i + 26] + Tm[(i + 26) * NTAG + j] - m1);
                sd += expf(alpha[i + 39] + Tm[(i + 39) * NTAG + j] - m1);
            }
            anew = m1 + logf((sa + sb) + (sc + sd)) + frow[j];
        } else if (wv == 1 && j < NTAG) {
            float va = -1e30f, vb = -1e30f, vc = -1e30f, vd = -1e30f;
            int ia = 0, ib = 13, ic = 26, id2 = 39;
            for (int i = 0; i < 13; i++) {
                float s0 = valpha[i]      + Tm[i * NTAG + j];        if (s0 > va) { va = s0; ia = i; }
                float s1 = valpha[i + 13] + Tm[(i + 13) * NTAG + j]; if (s1 > vb) { vb = s1; ib = i + 13; }
                float s2 = valpha[i + 26] + Tm[(i + 26) * NTAG + j]; if (s2 > vc) { vc = s2; ic = i + 26; }
                float s3 = valpha[i + 39] + Tm[(i + 39) * NTAG + j]; if (s3 > vd) { vd = s3; id2 = i + 39; }
            }
            float vm = va; arg = ia;
            if (vb > vm) { vm = vb; arg = ib; }
            if (vc > vm) { vm = vc; arg = ic; }
            if (vd > vm) { vm = vd; arg = id2; }
            vnew = vm + frow[j];
        }
        __syncthreads();
        if (wv == 0 && j < NTAG) {
            alpha[j] = anew;
        } else if (wv == 1 && j < NTAG) {
            valpha[j] = vnew;
            bp[t - 1][j] = (unsigned char)arg;
        }
        __syncthreads();
    }
    if (tid < NTAG) {
        red[tid]  = alpha[tid] + Tm[tid * NTAG + TSTOP];
        red2[tid] = valpha[tid] + Tm[tid * NTAG + TSTOP];
    }
    __syncthreads();
    // wave0: parallel gold transition+emission sum over t=1..len-1
    float gpart = 0.f;
    if (wv == 0) {
        const int* lab = blabel + b * TT;
        for (int t = 1 + j; t < len; t += 64)
            gpart += Tm[lab[t - 1] * NTAG + lab[t]] + fb[(size_t)t * NTAG + lab[t]];
#pragma unroll
        for (int m = 32; m; m >>= 1) gpart += __shfl_xor(gpart, m);
    }
    if (tid == 64) {
        int best = 0;
        float vm = red2[0];
        for (int i = 1; i < NTAG; i++)
            if (red2[i] > vm) { vm = red2[i]; best = i; }
        float* ot = outtags + (size_t)b * TT;
        int tag = best;
        ot[len - 1] = (float)tag;
        for (int t = len - 2; t >= 0; t--) {
            tag = bp[t][tag];
            ot[t] = (float)tag;
        }
        for (int t = len; t < TT; t++) ot[t] = 0.f;
    }
    if (tid == 0) {
        float m1 = red[0];
        for (int i = 1; i < NTAG; i++) m1 = fmaxf(m1, red[i]);
        float ssum = 0.f;
        for (int i = 0; i < NTAG; i++) ssum += expf(red[i] - m1);
        float Zg = m1 + logf(ssum);
        const int* lab = blabel + b * TT;
        float goldv = Tm[TSTART * NTAG + lab[0]] + fb[lab[0]] + gpart
                    + Tm[lab[len - 1] * NTAG + TSTOP];
        lossb[b] = Zg - goldv;
        __threadfence();
        unsigned old = atomicAdd(ctr, 1u);
        if (old == BB - 1) {                         // last block reduces (fixed order)
            __threadfence();
            float stot = 0.f;
            for (int i = 0; i < BB; i++) stot += lossb[i];
            out[0] = stot;
        }
    }
}

extern "C" void kernel_launch(void* const* d_in, const int* in_sizes, int n_in,
                              void* d_out, int out_size, void* d_ws, size_t ws_size,
                              hipStream_t stream) {
    const int* batch_word     = (const int*)d_in[0];
    const int* batch_features = (const int*)d_in[1];
    const int* batch_wordlen  = (const int*)d_in[2];
    const int* batch_char     = (const int*)d_in[3];
    const int* batch_recover  = (const int*)d_in[5];
    const int* batch_label    = (const int*)d_in[7];
    const float* char_emb = (const float*)d_in[8];
    const float* conv_w   = (const float*)d_in[9];
    const float* conv_b   = (const float*)d_in[10];
    const float* word_emb = (const float*)d_in[11];
    const float* feat_emb = (const float*)d_in[12];
    const float* w_ih_f   = (const float*)d_in[13];
    const float* w_hh_f   = (const float*)d_in[14];
    const float* b_f      = (const float*)d_in[15];
    const float* w_ih_b   = (const float*)d_in[16];
    const float* w_hh_b   = (const float*)d_in[17];
    const float* b_b      = (const float*)d_in[18];
    const float* proj_w   = (const float*)d_in[19];
    const float* proj_b   = (const float*)d_in[20];
    const float* trans    = (const float*)d_in[21];

    char* ws = (char*)d_ws;
    float* pooled   = (float*)(ws + OFF_POOL);
    _Float16* xh    = (_Float16*)(ws + OFF_XH);
    _Float16* wh16f = (_Float16*)(ws + OFF_W16F);
    _Float16* wh16b = (_Float16*)(ws + OFF_W16B);
    float* h_f    = (float*)(ws + OFF_HF);
    float* h_b    = (float*)(ws + OFF_HB);
    float* xs_f   = (float*)(ws + OFF_XSF);
    float* xs_b   = (float*)(ws + OFF_XSB);
    float* feats  = (float*)(ws + OFF_FEATS);
    _Float16* wh_f = (_Float16*)(ws + OFF_WPF);
    _Float16* wh_b = (_Float16*)(ws + OFF_WPB);
    float* lossb  = (float*)(ws + OFF_LOSSB);
    unsigned* ctr = (unsigned*)(ws + OFF_CTR);

    k_front<<<CHARCNN_BLOCKS + PREP_BLOCKS, 256, 0, stream>>>(
        batch_char, char_emb, conv_w, conv_b, pooled,
        w_hh_f, w_hh_b, w_ih_f, w_ih_b, wh_f, wh_b, wh16f, wh16b, ctr);
    k_concat<<<(BB * TT) / 8, 256, 0, stream>>>(batch_word, batch_features, batch_recover,
                                                word_emb, feat_emb, pooled, xh);
    k_gemm16b<<<dim3(G4 / 64, (BB * TT) / 128), 256, 0, stream>>>(xh, wh16f, wh16b,
                                                                  b_f, b_b, xs_f, xs_b);
    k_lstm<<<128, 1024, 0, stream>>>(xs_f, xs_b, wh_f, wh_b, batch_wordlen, h_f, h_b);
    k_proj<<<(BB * TT) / 64, 256, 0, stream>>>(h_f, h_b, proj_w, proj_b, feats);
    k_crf<<<BB, 128, 0, stream>>>(feats, trans, batch_wordlen, batch_label,
                                  lossb, (float*)d_out + 1, ctr, (float*)d_out);
}

// Round 16
// 1595.663 us; speedup vs baseline: 1.1984x; 1.0659x over previous
//
#include <hip/hip_runtime.h>
#include <hip/hip_bf16.h>
#include <math.h>

#define BB 64
#define TT 256
#define LCH 16
#define DC 50
#define CHN 100
#define DW 300
#define DF 20
#define HID 256
#define G4 1024
#define INDIM 420
#define KPAD 448
#define NTAG 52
#define TSTART 50
#define TSTOP 51

// ------------------- workspace layout (bytes) -------------------
static constexpr size_t OFF_POOL  = 0;                       // 6,553,600 (dead after concat)
static constexpr size_t OFF_XH    = 6553600;                 // 14,680,064 f16 -> 21,233,664
static constexpr size_t OFF_W16F  = 21233664;                // 917,504 f16 w_ih fwd
static constexpr size_t OFF_W16B  = 22151168;                // -> 23,068,672
static constexpr size_t OFF_HF    = 0;                       // 16,777,216 (lstm output)
static constexpr size_t OFF_HB    = 16777216;                // -> 33,554,432
static constexpr size_t OFF_XSF   = 34078720;                // 67,108,864
static constexpr size_t OFF_XSB   = 101187584;               // -> 168,296,448
static constexpr size_t OFF_FEATS = 168296448;               // 3,407,872 -> 171,704,320
static constexpr size_t OFF_WPF   = 171704320;               // 512 KB fp16 packed W_hh fwd
static constexpr size_t OFF_WPB   = 172752896;               // 512 KB fp16 packed W_hh bwd
static constexpr size_t OFF_LOSSB = 173801472;               // 256 B (64 floats)
static constexpr size_t OFF_CTR   = 173801728;               // 4 B (unsigned counter)

typedef _Float16 v2h __attribute__((ext_vector_type(2)));
typedef _Float16 f16x8 __attribute__((ext_vector_type(8)));
typedef float f32x4 __attribute__((ext_vector_type(4)));
union UH2 { unsigned u; v2h h; };
__device__ __forceinline__ float fdot2u(unsigned a, unsigned b, float c) {
    UH2 x, y; x.u = a; y.u = b;
    return __builtin_amdgcn_fdot2(x.h, y.h, c, false);
}
__device__ __forceinline__ float dot8(uint4 w, uint4 h, float acc) {
    acc = fdot2u(w.x, h.x, acc);
    acc = fdot2u(w.y, h.y, acc);
    acc = fdot2u(w.z, h.z, acc);
    acc = fdot2u(w.w, h.w, acc);
    return acc;
}
#define KEEPU4(v) asm volatile("" : "+v"((v).x), "+v"((v).y), "+v"((v).z), "+v"((v).w))

__device__ __forceinline__ float sigm(float x) { return 1.0f / (1.0f + expf(-x)); }

// ================= fused front kernel: charcnn (blocks 0..2047) +
//                   prep pack/cvt (blocks 2048..7679) + counter zero ==========
#define CHARCNN_BLOCKS 2048
#define PREP_BLOCKS 5632

__device__ __forceinline__ void packh_one(const float* __restrict__ w,
                                          _Float16* __restrict__ wph, int e) {
    int r  = e & 7;
    int j  = (e >> 3) & 255;
    int k8 = (e >> 11) & 7;
    int g  = (e >> 14) & 3;
    int s  = (e >> 16) & 3;
    wph[e] = (_Float16)w[(g * 256 + j) * HID + (s * 64 + k8 * 8 + r)];
}
__device__ __forceinline__ void cvtw_one(const float* __restrict__ w,
                                         _Float16* __restrict__ wh, int e) {
    int row = e / KPAD, k = e % KPAD;
    wh[e] = (k < INDIM) ? (_Float16)w[row * INDIM + k] : (_Float16)0.f;
}

__global__ __launch_bounds__(256) void k_front(const int* __restrict__ bchar,
                                               const float* __restrict__ cemb,
                                               const float* __restrict__ cw,
                                               const float* __restrict__ cb,
                                               float* __restrict__ pooled,
                                               const float* __restrict__ whf,
                                               const float* __restrict__ whb,
                                               const float* __restrict__ wihf,
                                               const float* __restrict__ wihb,
                                               _Float16* __restrict__ wpf,
                                               _Float16* __restrict__ wpb,
                                               _Float16* __restrict__ wh16f,
                                               _Float16* __restrict__ wh16b,
                                               unsigned* __restrict__ ctr) {
    __shared__ float cwsh[150][100];   // [d*3+q][c], 60 KB
    __shared__ float ET[2][DC][20];
    __shared__ int ids[2][LCH];
    int tid = threadIdx.x;
    if (blockIdx.x >= CHARCNN_BLOCKS) {
        // ---- prep body ----
        int e = (blockIdx.x - CHARCNN_BLOCKS) * 256 + tid;
        if (e == 0) *ctr = 0u;                       // zero last-block counter
        if (e < 262144)                packh_one(whf, wpf, e);
        else if (e < 524288)           packh_one(whb, wpb, e - 262144);
        else if (e < 524288 + 458752)  cvtw_one(wihf, wh16f, e - 524288);
        else if (e < 524288 + 917504)  cvtw_one(wihb, wh16b, e - 983040);
        return;
    }
    // ---- charcnn body: 8 words/block; cwsh staged COALESCED (c=i/150,row=i%150)
    int wbase = blockIdx.x * 8;
    for (int i = tid; i < 15000; i += 256) {
        int c = i / 150, row = i % 150;              // consecutive tid -> consecutive addr
        cwsh[row][c] = cw[i];
    }
    int half = tid >> 7, c = tid & 127;
    float bcv = (c < CHN) ? cb[c] : 0.f;
    for (int g = 0; g < 8; g += 2) {
        __syncthreads();
        if (tid < 32) ids[tid >> 4][tid & 15] = bchar[(wbase + g + (tid >> 4)) * LCH + (tid & 15)];
        __syncthreads();
        for (int s2 = tid; s2 < 2 * DC * 18; s2 += 256) {
            int w2 = s2 / 900, rem = s2 % 900;
            int d = rem / 18, l = rem % 18;
            float v = 0.f;
            if (l >= 1 && l <= 16) v = cemb[ids[w2][l - 1] * DC + d];
            ET[w2][d][l] = v;
        }
        __syncthreads();
        if (c < CHN) {
            float acc[16];
#pragma unroll
            for (int l = 0; l < 16; l++) acc[l] = 0.f;
            for (int d = 0; d < DC; d++) {
                float e[18];
                float4 t0 = *(const float4*)&ET[half][d][0];
                float4 t1 = *(const float4*)&ET[half][d][4];
                float4 t2 = *(const float4*)&ET[half][d][8];
                float4 t3 = *(const float4*)&ET[half][d][12];
                e[0]=t0.x; e[1]=t0.y; e[2]=t0.z; e[3]=t0.w;
                e[4]=t1.x; e[5]=t1.y; e[6]=t1.z; e[7]=t1.w;
                e[8]=t2.x; e[9]=t2.y; e[10]=t2.z; e[11]=t2.w;
                e[12]=t3.x; e[13]=t3.y; e[14]=t3.z; e[15]=t3.w;
                e[16]=ET[half][d][16]; e[17]=ET[half][d][17];
                float w0 = cwsh[d * 3 + 0][c];
                float w1 = cwsh[d * 3 + 1][c];
                float w2 = cwsh[d * 3 + 2][c];
#pragma unroll
                for (int l = 0; l < 16; l++)
                    acc[l] += w0 * e[l] + w1 * e[l + 1] + w2 * e[l + 2];
            }
            float m = acc[0];
#pragma unroll
            for (int l = 1; l < 16; l++) m = fmaxf(m, acc[l]);
            pooled[(wbase + g + half) * CHN + c] = m + bcv;
        }
    }
}

// ---- assemble xh[16384][448] f16; 8 words per block, 256 threads
__global__ __launch_bounds__(256) void k_concat(const int* __restrict__ word,
                                                const int* __restrict__ featsidx,
                                                const int* __restrict__ recover,
                                                const float* __restrict__ wemb,
                                                const float* __restrict__ femb,
                                                const float* __restrict__ pooled,
                                                _Float16* __restrict__ xh) {
    int tid = threadIdx.x;
    for (int wi = 0; wi < 8; wi++) {
        int w = blockIdx.x * 8 + wi;
        int b = w >> 8;
        int wid = word[w];
        _Float16* xr = xh + (size_t)w * KPAD;
        for (int c = tid; c < DW; c += 256) xr[c] = (_Float16)wemb[(size_t)wid * DW + c];
        int rc = recover[w];
        if (tid < CHN) xr[DW + tid] = (_Float16)pooled[rc * CHN + tid];
        if (tid < DF)  xr[DW + CHN + tid] = (_Float16)femb[featsidx[b] * DF + tid];
        if (tid >= 100 && tid < 100 + (KPAD - INDIM)) xr[INDIM + (tid - 100)] = (_Float16)0.f;
    }
}

// ---- fused f16 MFMA GEMM for BOTH directions, LDS-staged (coalesced).
__global__ __launch_bounds__(256, 4) void k_gemm16b(const _Float16* __restrict__ A,
                                                    const _Float16* __restrict__ Bf,
                                                    const _Float16* __restrict__ Bb,
                                                    const float* __restrict__ biasf,
                                                    const float* __restrict__ biasb,
                                                    float* __restrict__ Cf,
                                                    float* __restrict__ Cb) {
    __shared__ __align__(16) _Float16 Asl[128 * 72];
    __shared__ __align__(16) _Float16 Bfl[64 * 72];
    __shared__ __align__(16) _Float16 Bbl[64 * 72];
    int tid = threadIdx.x;
    int wv = tid >> 6, l = tid & 63;
    int lm = l & 15, lk = l >> 4;
    int n0 = blockIdx.x * 64, m0 = blockIdx.y * 128;
    f32x4 z = {0.f, 0.f, 0.f, 0.f};
    f32x4 af0 = z, af1 = z, af2 = z, af3 = z;
    f32x4 ag0 = z, ag1 = z, ag2 = z, ag3 = z;
    f32x4 ab0 = z, ab1 = z, ab2 = z, ab3 = z;
    f32x4 ac0 = z, ac1 = z, ac2 = z, ac3 = z;
    for (int k0 = 0; k0 < KPAD; k0 += 64) {
        __syncthreads();
#pragma unroll
        for (int q = 0; q < 4; q++) {
            int ch = tid + q * 256;
            int r = ch >> 3, cc = ch & 7;
            ((uint4*)Asl)[r * 9 + cc] =
                *(const uint4*)&A[(size_t)(m0 + r) * KPAD + k0 + cc * 8];
        }
#pragma unroll
        for (int q = 0; q < 2; q++) {
            int ch = tid + q * 256;
            int r = ch >> 3, cc = ch & 7;
            ((uint4*)Bfl)[r * 9 + cc] =
                *(const uint4*)&Bf[(size_t)(n0 + r) * KPAD + k0 + cc * 8];
            ((uint4*)Bbl)[r * 9 + cc] =
                *(const uint4*)&Bb[(size_t)(n0 + r) * KPAD + k0 + cc * 8];
        }
        __syncthreads();
#pragma unroll
        for (int kstep = 0; kstep < 2; kstep++) {
            int kk = kstep * 4 + lk;
            f16x8 a0 = ((const f16x8*)Asl)[(wv * 32 + lm) * 9 + kk];
            f16x8 a1 = ((const f16x8*)Asl)[(wv * 32 + 16 + lm) * 9 + kk];
            f16x8 b0 = ((const f16x8*)Bfl)[(0 * 16 + lm) * 9 + kk];
            f16x8 b1 = ((const f16x8*)Bfl)[(1 * 16 + lm) * 9 + kk];
            f16x8 b2 = ((const f16x8*)Bfl)[(2 * 16 + lm) * 9 + kk];
            f16x8 b3 = ((const f16x8*)Bfl)[(3 * 16 + lm) * 9 + kk];
            f16x8 c0 = ((const f16x8*)Bbl)[(0 * 16 + lm) * 9 + kk];
            f16x8 c1 = ((const f16x8*)Bbl)[(1 * 16 + lm) * 9 + kk];
            f16x8 c2 = ((const f16x8*)Bbl)[(2 * 16 + lm) * 9 + kk];
            f16x8 c3 = ((const f16x8*)Bbl)[(3 * 16 + lm) * 9 + kk];
            af0 = __builtin_amdgcn_mfma_f32_16x16x32_f16(a0, b0, af0, 0, 0, 0);
            af1 = __builtin_amdgcn_mfma_f32_16x16x32_f16(a0, b1, af1, 0, 0, 0);
            af2 = __builtin_amdgcn_mfma_f32_16x16x32_f16(a0, b2, af2, 0, 0, 0);
            af3 = __builtin_amdgcn_mfma_f32_16x16x32_f16(a0, b3, af3, 0, 0, 0);
            ag0 = __builtin_amdgcn_mfma_f32_16x16x32_f16(a1, b0, ag0, 0, 0, 0);
            ag1 = __builtin_amdgcn_mfma_f32_16x16x32_f16(a1, b1, ag1, 0, 0, 0);
            ag2 = __builtin_amdgcn_mfma_f32_16x16x32_f16(a1, b2, ag2, 0, 0, 0);
            ag3 = __builtin_amdgcn_mfma_f32_16x16x32_f16(a1, b3, ag3, 0, 0, 0);
            ab0 = __builtin_amdgcn_mfma_f32_16x16x32_f16(a0, c0, ab0, 0, 0, 0);
            ab1 = __builtin_amdgcn_mfma_f32_16x16x32_f16(a0, c1, ab1, 0, 0, 0);
            ab2 = __builtin_amdgcn_mfma_f32_16x16x32_f16(a0, c2, ab2, 0, 0, 0);
            ab3 = __builtin_amdgcn_mfma_f32_16x16x32_f16(a0, c3, ab3, 0, 0, 0);
            ac0 = __builtin_amdgcn_mfma_f32_16x16x32_f16(a1, c0, ac0, 0, 0, 0);
            ac1 = __builtin_amdgcn_mfma_f32_16x16x32_f16(a1, c1, ac1, 0, 0, 0);
            ac2 = __builtin_amdgcn_mfma_f32_16x16x32_f16(a1, c2, ac2, 0, 0, 0);
            ac3 = __builtin_amdgcn_mfma_f32_16x16x32_f16(a1, c3, ac3, 0, 0, 0);
        }
    }
    f32x4 fa[2][4] = {{af0, af1, af2, af3}, {ag0, ag1, ag2, ag3}};
    f32x4 ba[2][4] = {{ab0, ab1, ab2, ab3}, {ac0, ac1, ac2, ac3}};
#pragma unroll
    for (int mi = 0; mi < 2; mi++) {
        int orow = m0 + wv * 32 + mi * 16 + lk * 4;
#pragma unroll
        for (int jn = 0; jn < 4; jn++) {
            int col = n0 + jn * 16 + lm;
            float bvf = biasf[col], bvb = biasb[col];
#pragma unroll
            for (int r = 0; r < 4; r++) {
                Cf[(size_t)(orow + r) * G4 + col] = fa[mi][jn][r] + bvf;
                Cb[(size_t)(orow + r) * G4 + col] = ba[mi][jn][r] + bvb;
            }
        }
    }
}

// ---- masked BiLSTM (r13 structure, untouched): o-gate in 128 KB LDS; g-gate
// pinned in 32 VGPRs; i,f streamed 256 KB/step from L2 (per-CU L2-path floor).
__global__ __launch_bounds__(1024, 4) void k_lstm(const float* __restrict__ xs_f,
                                               const float* __restrict__ xs_b,
                                               const _Float16* __restrict__ wh_f,
                                               const _Float16* __restrict__ wh_b,
                                               const int* __restrict__ wlen,
                                               float* __restrict__ h_f,
                                               float* __restrict__ h_b) {
    int b = blockIdx.x & 63, d = blockIdx.x >> 6;
    const float* xs = d ? xs_b : xs_f;
    const uint4* wp4 = (const uint4*)(d ? wh_b : wh_f);
    float* ho = d ? h_b : h_f;
    int len = wlen[b];
    __shared__ uint4 olds4[8192];                 // o-gate weights, 128 KB
    __shared__ _Float16 __align__(16) hh[256];    // f16 h state
    __shared__ float part[4][4][256];             // [s][gate][unit], 16 KB
    int tid = threadIdx.x;
    int j = tid & 255, s = tid >> 8;
    const uint4* pi = wp4 + (size_t)((s * 4 + 0) * 8) * 256 + j;   // i (streamed)
    const uint4* pf = wp4 + (size_t)((s * 4 + 1) * 8) * 256 + j;   // f (streamed)
    uint4 wg[8];                                   // g-gate resident (32 VGPRs)
    {
        const uint4* pg = wp4 + (size_t)((s * 4 + 2) * 8) * 256 + j;
        const uint4* po = wp4 + (size_t)((s * 4 + 3) * 8) * 256 + j;
#pragma unroll
        for (int k8 = 0; k8 < 8; k8++) {
            wg[k8] = pg[k8 * 256];
            olds4[k8 * 1024 + tid] = po[k8 * 256];
        }
    }
#pragma unroll
    for (int k8 = 0; k8 < 8; k8++) KEEPU4(wg[k8]);
    if (tid < 128) ((unsigned*)hh)[tid] = 0u;
    float c = 0.f;
    const uint4* hsh4 = (const uint4*)hh;
    __syncthreads();
    for (int ss = 0; ss < len; ++ss) {
        int t = d ? (len - 1 - ss) : ss;
        float xv0, xv1, xv2, xv3;
        if (tid < 256) {
            const float* xr = xs + (size_t)(b * TT + t) * G4;
            xv0 = xr[tid];
            xv1 = xr[256 + tid];
            xv2 = xr[512 + tid];
            xv3 = xr[768 + tid];
        }
        asm volatile("" : "+v"(pi), "+v"(pf));
        float a0 = 0.f, a1 = 0.f, a2 = 0.f, a3 = 0.f;
#pragma unroll
        for (int k8 = 0; k8 < 8; k8++) {
            uint4 h4 = hsh4[s * 8 + k8];                       // broadcast
            uint4 wi = pi[k8 * 256];
            uint4 wf = pf[k8 * 256];
            uint4 wo = olds4[k8 * 1024 + tid];
            a0 = dot8(wi, h4, a0);
            a1 = dot8(wf, h4, a1);
            a2 = dot8(wg[k8], h4, a2);
            a3 = dot8(wo, h4, a3);
        }
        part[s][0][j] = a0;
        part[s][1][j] = a1;
        part[s][2][j] = a2;
        part[s][3][j] = a3;
        __syncthreads();
        if (tid < 256) {
            float s0 = part[0][0][tid] + part[1][0][tid] + part[2][0][tid] + part[3][0][tid] + xv0;
            float s1 = part[0][1][tid] + part[1][1][tid] + part[2][1][tid] + part[3][1][tid] + xv1;
            float s2 = part[0][2][tid] + part[1][2][tid] + part[2][2][tid] + part[3][2][tid] + xv2;
            float s3 = part[0][3][tid] + part[1][3][tid] + part[2][3][tid] + part[3][3][tid] + xv3;
            float ig = sigm(s0), fg = sigm(s1), zg = tanhf(s2), og = sigm(s3);
            c = fg * c + ig * zg;
            float h = og * tanhf(c);
            hh[tid] = (_Float16)h;
            ho[(size_t)(b * TT + t) * HID + tid] = h;
        }
        __syncthreads();
    }
}

// ---- projection: proj_w LDS-resident (stride-513 pad), 64 words per block
__global__ __launch_bounds__(256) void k_proj(const float* __restrict__ hf,
                                              const float* __restrict__ hb,
                                              const float* __restrict__ pw,
                                              const float* __restrict__ pb,
                                              float* __restrict__ feats) {
    __shared__ float pwsh[NTAG][513];
    __shared__ float hsh[512];
    __shared__ float part2[4][NTAG];
    int tid = threadIdx.x;
    int w0 = blockIdx.x * 64;
    for (int i = tid; i < NTAG * 512; i += 256) pwsh[i >> 9][i & 511] = pw[i];
    __syncthreads();
    int q = tid >> 6, t = tid & 63;
    for (int wi = 0; wi < 64; wi++) {
        int w = w0 + wi;
        hsh[tid]       = hf[(size_t)w * HID + tid];
        hsh[256 + tid] = hb[(size_t)w * HID + tid];
        __syncthreads();
        if (t < NTAG) {
            float ssum = 0.f;
            int k0 = q * 128;
            for (int k = 0; k < 128; k++) ssum += pwsh[t][k0 + k] * hsh[k0 + k];
            part2[q][t] = ssum;
        }
        __syncthreads();
        if (tid < NTAG)
            feats[(size_t)w * NTAG + tid] =
                part2[0][tid] + part2[1][tid] + part2[2][tid] + part2[3][tid] + pb[tid];
        __syncthreads();
    }
}

// ---- CRF: 128 single-wave blocks. Blocks 0..63: forward logsumexp + gold +
// loss (+ last-block total). Blocks 64..127: viterbi + backtrace.
// Wave-synchronous: no __syncthreads in the t-loop (single wave; LDS ops are
// program-ordered within a wave; wave_barrier = free compile-time fence).
__global__ __launch_bounds__(64) void k_crf(const float* __restrict__ feats,
                                            const float* __restrict__ trans,
                                            const int* __restrict__ wlen,
                                            const int* __restrict__ blabel,
                                            float* __restrict__ lossb,
                                            float* __restrict__ outtags,
                                            unsigned* __restrict__ ctr,
                                            float* __restrict__ out) {
    __shared__ float Tm[NTAG * NTAG];
    __shared__ float st[NTAG];                    // alpha (fwd) or valpha (vit)
    __shared__ unsigned char bp[TT - 1][NTAG];    // used by vit blocks only
    int bid = blockIdx.x;
    int b = bid & 63;
    bool vit = bid >= BB;
    int j = threadIdx.x;
    for (int s = j; s < NTAG * NTAG; s += 64) Tm[s] = trans[s];
    __builtin_amdgcn_wave_barrier();
    int len = wlen[b];
    const float* fb = feats + (size_t)b * TT * NTAG;
    if (j < NTAG) st[j] = fb[j] + Tm[TSTART * NTAG + j];
    __builtin_amdgcn_wave_barrier();
    if (!vit) {
        // -------- forward recursion (alpha) --------
        float frow = (j < NTAG && len > 1) ? fb[NTAG + j] : 0.f;
        for (int t = 1; t < len; t++) {
            float frow_nxt = (j < NTAG && t + 1 < len) ? fb[(size_t)(t + 1) * NTAG + j] : 0.f;
            float anew = 0.f;
            if (j < NTAG) {
                float ma = -1e30f, mb = -1e30f, mc = -1e30f, md = -1e30f;
                for (int i = 0; i < 13; i++) {
                    ma = fmaxf(ma, st[i]      + Tm[i * NTAG + j]);
                    mb = fmaxf(mb, st[i + 13] + Tm[(i + 13) * NTAG + j]);
                    mc = fmaxf(mc, st[i + 26] + Tm[(i + 26) * NTAG + j]);
                    md = fmaxf(md, st[i + 39] + Tm[(i + 39) * NTAG + j]);
                }
                float m1 = fmaxf(fmaxf(ma, mb), fmaxf(mc, md));
                float sa = 0.f, sb = 0.f, sc = 0.f, sd = 0.f;
                for (int i = 0; i < 13; i++) {
                    sa += expf(st[i]      + Tm[i * NTAG + j] - m1);
                    sb += expf(st[i + 13] + Tm[(i + 13) * NTAG + j] - m1);
                    sc += expf(st[i + 26] + Tm[(i + 26) * NTAG + j] - m1);
                    sd += expf(st[i + 39] + Tm[(i + 39) * NTAG + j] - m1);
                }
                anew = m1 + logf((sa + sb) + (sc + sd)) + frow;
            }
            __builtin_amdgcn_wave_barrier();
            if (j < NTAG) st[j] = anew;
            __builtin_amdgcn_wave_barrier();
            frow = frow_nxt;
        }
        // -------- terminal Z via shuffle butterflies --------
        float red = (j < NTAG) ? st[j] + Tm[j * NTAG + TSTOP] : -1e30f;
        float m1 = red;
#pragma unroll
        for (int m = 32; m; m >>= 1) m1 = fmaxf(m1, __shfl_xor(m1, m));
        float e = (j < NTAG) ? expf(red - m1) : 0.f;
        float ssum = e;
#pragma unroll
        for (int m = 32; m; m >>= 1) ssum += __shfl_xor(ssum, m);
        // -------- gold score (parallel over t, strided) --------
        const int* lab = blabel + b * TT;
        float gpart = 0.f;
        for (int t = 1 + j; t < len; t += 64)
            gpart += Tm[lab[t - 1] * NTAG + lab[t]] + fb[(size_t)t * NTAG + lab[t]];
#pragma unroll
        for (int m = 32; m; m >>= 1) gpart += __shfl_xor(gpart, m);
        if (j == 0) {
            float Zg = m1 + logf(ssum);
            float goldv = Tm[TSTART * NTAG + lab[0]] + fb[lab[0]] + gpart
                        + Tm[lab[len - 1] * NTAG + TSTOP];
            lossb[b] = Zg - goldv;
            __threadfence();
            unsigned old = atomicAdd(ctr, 1u);
            if (old == BB - 1) {                     // last fwd block reduces (fixed order)
                __threadfence();
                float stot = 0.f;
                for (int i = 0; i < BB; i++) stot += lossb[i];
                out[0] = stot;
            }
        }
    } else {
        // -------- viterbi recursion (valpha + backpointers) --------
        float frow = (j < NTAG && len > 1) ? fb[NTAG + j] : 0.f;
        for (int t = 1; t < len; t++) {
            float frow_nxt = (j < NTAG && t + 1 < len) ? fb[(size_t)(t + 1) * NTAG + j] : 0.f;
            float vnew = 0.f;
            int arg = 0;
            if (j < NTAG) {
                float va = -1e30f, vb = -1e30f, vc = -1e30f, vd = -1e30f;
                int ia = 0, ib = 13, ic = 26, id2 = 39;
                for (int i = 0; i < 13; i++) {
                    float s0 = st[i]      + Tm[i * NTAG + j];        if (s0 > va) { va = s0; ia = i; }
                    float s1 = st[i + 13] + Tm[(i + 13) * NTAG + j]; if (s1 > vb) { vb = s1; ib = i + 13; }
                    float s2 = st[i + 26] + Tm[(i + 26) * NTAG + j]; if (s2 > vc) { vc = s2; ic = i + 26; }
                    float s3 = st[i + 39] + Tm[(i + 39) * NTAG + j]; if (s3 > vd) { vd = s3; id2 = i + 39; }
                }
                float vm = va; arg = ia;
                if (vb > vm) { vm = vb; arg = ib; }
                if (vc > vm) { vm = vc; arg = ic; }
                if (vd > vm) { vm = vd; arg = id2; }
                vnew = vm + frow;
            }
            __builtin_amdgcn_wave_barrier();
            if (j < NTAG) {
                st[j] = vnew;
                bp[t - 1][j] = (unsigned char)arg;
            }
            __builtin_amdgcn_wave_barrier();
            frow = frow_nxt;
        }
        if (j == 0) {
            int best = 0;
            float vm = st[0] + Tm[0 * NTAG + TSTOP];
            for (int i = 1; i < NTAG; i++) {
                float v = st[i] + Tm[i * NTAG + TSTOP];
                if (v > vm) { vm = v; best = i; }
            }
            float* ot = outtags + (size_t)b * TT;
            int tag = best;
            ot[len - 1] = (float)tag;
            for (int t = len - 2; t >= 0; t--) {
                tag = bp[t][tag];
                ot[t] = (float)tag;
            }
            for (int t = len; t < TT; t++) ot[t] = 0.f;
        }
    }
}

extern "C" void kernel_launch(void* const* d_in, const int* in_sizes, int n_in,
                              void* d_out, int out_size, void* d_ws, size_t ws_size,
                              hipStream_t stream) {
    const int* batch_word     = (const int*)d_in[0];
    const int* batch_features = (const int*)d_in[1];
    const int* batch_wordlen  = (const int*)d_in[2];
    const int* batch_char     = (const int*)d_in[3];
    const int* batch_recover  = (const int*)d_in[5];
    const int* batch_label    = (const int*)d_in[7];
    const float* char_emb = (const float*)d_in[8];
    const float* conv_w   = (const float*)d_in[9];
    const float* conv_b   = (const float*)d_in[10];
    const float* word_emb = (const float*)d_in[11];
    const float* feat_emb = (const float*)d_in[12];
    const float* w_ih_f   = (const float*)d_in[13];
    const float* w_hh_f   = (const float*)d_in[14];
    const float* b_f      = (const float*)d_in[15];
    const float* w_ih_b   = (const float*)d_in[16];
    const float* w_hh_b   = (const float*)d_in[17];
    const float* b_b      = (const float*)d_in[18];
    const float* proj_w   = (const float*)d_in[19];
    const float* proj_b   = (const float*)d_in[20];
    const float* trans    = (const float*)d_in[21];

    char* ws = (char*)d_ws;
    float* pooled   = (float*)(ws + OFF_POOL);
    _Float16* xh    = (_Float16*)(ws + OFF_XH);
    _Float16* wh16f = (_Float16*)(ws + OFF_W16F);
    _Float16* wh16b = (_Float16*)(ws + OFF_W16B);
    float* h_f    = (float*)(ws + OFF_HF);
    float* h_b    = (float*)(ws + OFF_HB);
    float* xs_f   = (float*)(ws + OFF_XSF);
    float* xs_b   = (float*)(ws + OFF_XSB);
    float* feats  = (float*)(ws + OFF_FEATS);
    _Float16* wh_f = (_Float16*)(ws + OFF_WPF);
    _Float16* wh_b = (_Float16*)(ws + OFF_WPB);
    float* lossb  = (float*)(ws + OFF_LOSSB);
    unsigned* ctr = (unsigned*)(ws + OFF_CTR);

    k_front<<<CHARCNN_BLOCKS + PREP_BLOCKS, 256, 0, stream>>>(
        batch_char, char_emb, conv_w, conv_b, pooled,
        w_hh_f, w_hh_b, w_ih_f, w_ih_b, wh_f, wh_b, wh16f, wh16b, ctr);
    k_concat<<<(BB * TT) / 8, 256, 0, stream>>>(batch_word, batch_features, batch_recover,
                                                word_emb, feat_emb, pooled, xh);
    k_gemm16b<<<dim3(G4 / 64, (BB * TT) / 128), 256, 0, stream>>>(xh, wh16f, wh16b,
                                                                  b_f, b_b, xs_f, xs_b);
    k_lstm<<<128, 1024, 0, stream>>>(xs_f, xs_b, wh_f, wh_b, batch_wordlen, h_f, h_b);
    k_proj<<<(BB * TT) / 64, 256, 0, stream>>>(h_f, h_b, proj_w, proj_b, feats);
    k_crf<<<2 * BB, 64, 0, stream>>>(feats, trans, batch_wordlen, batch_label,
                                     lossb, (float*)d_out + 1, ctr, (float*)d_out);
}

// Round 17
// 1499.497 us; speedup vs baseline: 1.2753x; 1.0641x over previous
//
#include <hip/hip_runtime.h>
#include <hip/hip_bf16.h>
#include <math.h>

#define BB 64
#define TT 256
#define LCH 16
#define DC 50
#define CHN 100
#define DW 300
#define DF 20
#define HID 256
#define G4 1024
#define INDIM 420
#define KPAD 448
#define NTAG 52
#define TSTART 50
#define TSTOP 51

// ------------------- workspace layout (bytes) -------------------
static constexpr size_t OFF_POOL  = 0;                       // 6,553,600 (dead after concat)
static constexpr size_t OFF_XH    = 6553600;                 // 14,680,064 f16 -> 21,233,664 (dead after gemm)
static constexpr size_t OFF_W16F  = 21233664;                // 917,504 f16 w_ih fwd
static constexpr size_t OFF_W16B  = 22151168;                // -> 23,068,672
static constexpr size_t OFF_PW16  = 23068672;                // 65,536 f16 proj_w -> 23,134,208
static constexpr size_t OFF_HCAT  = 0;                       // 16,777,216 f16 [16384][512] (lstm out)
static constexpr size_t OFF_XSF   = 34078720;                // 67,108,864
static constexpr size_t OFF_XSB   = 101187584;               // -> 168,296,448
static constexpr size_t OFF_FEATS = 168296448;               // 3,407,872 -> 171,704,320
static constexpr size_t OFF_WPF   = 171704320;               // 512 KB fp16 packed W_hh fwd
static constexpr size_t OFF_WPB   = 172752896;               // 512 KB fp16 packed W_hh bwd
static constexpr size_t OFF_LOSSB = 173801472;               // 256 B (64 floats)
static constexpr size_t OFF_CTR   = 173801728;               // 4 B (unsigned counter)

typedef _Float16 v2h __attribute__((ext_vector_type(2)));
typedef _Float16 f16x8 __attribute__((ext_vector_type(8)));
typedef float f32x4 __attribute__((ext_vector_type(4)));
union UH2 { unsigned u; v2h h; };
__device__ __forceinline__ float fdot2u(unsigned a, unsigned b, float c) {
    UH2 x, y; x.u = a; y.u = b;
    return __builtin_amdgcn_fdot2(x.h, y.h, c, false);
}
__device__ __forceinline__ float dot8(uint4 w, uint4 h, float acc) {
    acc = fdot2u(w.x, h.x, acc);
    acc = fdot2u(w.y, h.y, acc);
    acc = fdot2u(w.z, h.z, acc);
    acc = fdot2u(w.w, h.w, acc);
    return acc;
}
#define KEEPU4(v) asm volatile("" : "+v"((v).x), "+v"((v).y), "+v"((v).z), "+v"((v).w))

__device__ __forceinline__ float sigm(float x) { return 1.0f / (1.0f + expf(-x)); }

// ================= fused front kernel: charcnn (blocks 0..2047) +
//       prep pack/cvt incl. proj_w f16 (blocks 2048..) + counter zero ==========
#define CHARCNN_BLOCKS 2048
#define PREP_BLOCKS 5760          // ceil(1474560 / 256)

__device__ __forceinline__ void packh_one(const float* __restrict__ w,
                                          _Float16* __restrict__ wph, int e) {
    int r  = e & 7;
    int j  = (e >> 3) & 255;
    int k8 = (e >> 11) & 7;
    int g  = (e >> 14) & 3;
    int s  = (e >> 16) & 3;
    wph[e] = (_Float16)w[(g * 256 + j) * HID + (s * 64 + k8 * 8 + r)];
}
__device__ __forceinline__ void cvtw_one(const float* __restrict__ w,
                                         _Float16* __restrict__ wh, int e) {
    int row = e / KPAD, k = e % KPAD;
    wh[e] = (k < INDIM) ? (_Float16)w[row * INDIM + k] : (_Float16)0.f;
}

__global__ __launch_bounds__(256) void k_front(const int* __restrict__ bchar,
                                               const float* __restrict__ cemb,
                                               const float* __restrict__ cw,
                                               const float* __restrict__ cb,
                                               float* __restrict__ pooled,
                                               const float* __restrict__ whf,
                                               const float* __restrict__ whb,
                                               const float* __restrict__ wihf,
                                               const float* __restrict__ wihb,
                                               const float* __restrict__ pw,
                                               _Float16* __restrict__ wpf,
                                               _Float16* __restrict__ wpb,
                                               _Float16* __restrict__ wh16f,
                                               _Float16* __restrict__ wh16b,
                                               _Float16* __restrict__ pw16,
                                               unsigned* __restrict__ ctr) {
    __shared__ float cwsh[150][100];   // [d*3+q][c], 60 KB
    __shared__ float ET[2][DC][20];
    __shared__ int ids[2][LCH];
    int tid = threadIdx.x;
    if (blockIdx.x >= CHARCNN_BLOCKS) {
        // ---- prep body ----
        int e = (blockIdx.x - CHARCNN_BLOCKS) * 256 + tid;
        if (e == 0) *ctr = 0u;                       // zero last-block counter
        if (e < 262144)                packh_one(whf, wpf, e);
        else if (e < 524288)           packh_one(whb, wpb, e - 262144);
        else if (e < 983040)           cvtw_one(wihf, wh16f, e - 524288);
        else if (e < 1441792)          cvtw_one(wihb, wh16b, e - 983040);
        else if (e < 1474560) {
            int p = e - 1441792;                     // [64][512] f16, rows >= 52 zero
            int row = p >> 9;
            pw16[p] = (row < NTAG) ? (_Float16)pw[p - (64 - NTAG) * 0 - (row - row) + (row * 512 + (p & 511)) - p + p] : (_Float16)0.f;
            // simplified: row<52 -> pw[row*512 + (p&511)]
            pw16[p] = (row < NTAG) ? (_Float16)pw[row * 512 + (p & 511)] : (_Float16)0.f;
        }
        return;
    }
    // ---- charcnn body: 8 words/block; cwsh staged coalesced ----
    int wbase = blockIdx.x * 8;
    for (int i = tid; i < 15000; i += 256) {
        int c = i / 150, row = i % 150;
        cwsh[row][c] = cw[i];
    }
    int half = tid >> 7, c = tid & 127;
    float bcv = (c < CHN) ? cb[c] : 0.f;
    for (int g = 0; g < 8; g += 2) {
        __syncthreads();
        if (tid < 32) ids[tid >> 4][tid & 15] = bchar[(wbase + g + (tid >> 4)) * LCH + (tid & 15)];
        __syncthreads();
        for (int s2 = tid; s2 < 2 * DC * 18; s2 += 256) {
            int w2 = s2 / 900, rem = s2 % 900;
            int d = rem / 18, l = rem % 18;
            float v = 0.f;
            if (l >= 1 && l <= 16) v = cemb[ids[w2][l - 1] * DC + d];
            ET[w2][d][l] = v;
        }
        __syncthreads();
        if (c < CHN) {
            float acc[16];
#pragma unroll
            for (int l = 0; l < 16; l++) acc[l] = 0.f;
            for (int d = 0; d < DC; d++) {
                float e[18];
                float4 t0 = *(const float4*)&ET[half][d][0];
                float4 t1 = *(const float4*)&ET[half][d][4];
                float4 t2 = *(const float4*)&ET[half][d][8];
                float4 t3 = *(const float4*)&ET[half][d][12];
                e[0]=t0.x; e[1]=t0.y; e[2]=t0.z; e[3]=t0.w;
                e[4]=t1.x; e[5]=t1.y; e[6]=t1.z; e[7]=t1.w;
                e[8]=t2.x; e[9]=t2.y; e[10]=t2.z; e[11]=t2.w;
                e[12]=t3.x; e[13]=t3.y; e[14]=t3.z; e[15]=t3.w;
                e[16]=ET[half][d][16]; e[17]=ET[half][d][17];
                float w0 = cwsh[d * 3 + 0][c];
                float w1 = cwsh[d * 3 + 1][c];
                float w2 = cwsh[d * 3 + 2][c];
#pragma unroll
                for (int l = 0; l < 16; l++)
                    acc[l] += w0 * e[l] + w1 * e[l + 1] + w2 * e[l + 2];
            }
            float m = acc[0];
#pragma unroll
            for (int l = 1; l < 16; l++) m = fmaxf(m, acc[l]);
            pooled[(wbase + g + half) * CHN + c] = m + bcv;
        }
    }
}

// ---- assemble xh[16384][448] f16; 8 words per block, 256 threads
__global__ __launch_bounds__(256) void k_concat(const int* __restrict__ word,
                                                const int* __restrict__ featsidx,
                                                const int* __restrict__ recover,
                                                const float* __restrict__ wemb,
                                                const float* __restrict__ femb,
                                                const float* __restrict__ pooled,
                                                _Float16* __restrict__ xh) {
    int tid = threadIdx.x;
    for (int wi = 0; wi < 8; wi++) {
        int w = blockIdx.x * 8 + wi;
        int b = w >> 8;
        int wid = word[w];
        _Float16* xr = xh + (size_t)w * KPAD;
        for (int c = tid; c < DW; c += 256) xr[c] = (_Float16)wemb[(size_t)wid * DW + c];
        int rc = recover[w];
        if (tid < CHN) xr[DW + tid] = (_Float16)pooled[rc * CHN + tid];
        if (tid < DF)  xr[DW + CHN + tid] = (_Float16)femb[featsidx[b] * DF + tid];
        if (tid >= 100 && tid < 100 + (KPAD - INDIM)) xr[INDIM + (tid - 100)] = (_Float16)0.f;
    }
}

// ---- fused f16 MFMA GEMM for BOTH directions, LDS-staged (coalesced).
__global__ __launch_bounds__(256, 4) void k_gemm16b(const _Float16* __restrict__ A,
                                                    const _Float16* __restrict__ Bf,
                                                    const _Float16* __restrict__ Bb,
                                                    const float* __restrict__ biasf,
                                                    const float* __restrict__ biasb,
                                                    float* __restrict__ Cf,
                                                    float* __restrict__ Cb) {
    __shared__ __align__(16) _Float16 Asl[128 * 72];
    __shared__ __align__(16) _Float16 Bfl[64 * 72];
    __shared__ __align__(16) _Float16 Bbl[64 * 72];
    int tid = threadIdx.x;
    int wv = tid >> 6, l = tid & 63;
    int lm = l & 15, lk = l >> 4;
    int n0 = blockIdx.x * 64, m0 = blockIdx.y * 128;
    f32x4 z = {0.f, 0.f, 0.f, 0.f};
    f32x4 af0 = z, af1 = z, af2 = z, af3 = z;
    f32x4 ag0 = z, ag1 = z, ag2 = z, ag3 = z;
    f32x4 ab0 = z, ab1 = z, ab2 = z, ab3 = z;
    f32x4 ac0 = z, ac1 = z, ac2 = z, ac3 = z;
    for (int k0 = 0; k0 < KPAD; k0 += 64) {
        __syncthreads();
#pragma unroll
        for (int q = 0; q < 4; q++) {
            int ch = tid + q * 256;
            int r = ch >> 3, cc = ch & 7;
            ((uint4*)Asl)[r * 9 + cc] =
                *(const uint4*)&A[(size_t)(m0 + r) * KPAD + k0 + cc * 8];
        }
#pragma unroll
        for (int q = 0; q < 2; q++) {
            int ch = tid + q * 256;
            int r = ch >> 3, cc = ch & 7;
            ((uint4*)Bfl)[r * 9 + cc] =
                *(const uint4*)&Bf[(size_t)(n0 + r) * KPAD + k0 + cc * 8];
            ((uint4*)Bbl)[r * 9 + cc] =
                *(const uint4*)&Bb[(size_t)(n0 + r) * KPAD + k0 + cc * 8];
        }
        __syncthreads();
#pragma unroll
        for (int kstep = 0; kstep < 2; kstep++) {
            int kk = kstep * 4 + lk;
            f16x8 a0 = ((const f16x8*)Asl)[(wv * 32 + lm) * 9 + kk];
            f16x8 a1 = ((const f16x8*)Asl)[(wv * 32 + 16 + lm) * 9 + kk];
            f16x8 b0 = ((const f16x8*)Bfl)[(0 * 16 + lm) * 9 + kk];
            f16x8 b1 = ((const f16x8*)Bfl)[(1 * 16 + lm) * 9 + kk];
            f16x8 b2 = ((const f16x8*)Bfl)[(2 * 16 + lm) * 9 + kk];
            f16x8 b3 = ((const f16x8*)Bfl)[(3 * 16 + lm) * 9 + kk];
            f16x8 c0 = ((const f16x8*)Bbl)[(0 * 16 + lm) * 9 + kk];
            f16x8 c1 = ((const f16x8*)Bbl)[(1 * 16 + lm) * 9 + kk];
            f16x8 c2 = ((const f16x8*)Bbl)[(2 * 16 + lm) * 9 + kk];
            f16x8 c3 = ((const f16x8*)Bbl)[(3 * 16 + lm) * 9 + kk];
            af0 = __builtin_amdgcn_mfma_f32_16x16x32_f16(a0, b0, af0, 0, 0, 0);
            af1 = __builtin_amdgcn_mfma_f32_16x16x32_f16(a0, b1, af1, 0, 0, 0);
            af2 = __builtin_amdgcn_mfma_f32_16x16x32_f16(a0, b2, af2, 0, 0, 0);
            af3 = __builtin_amdgcn_mfma_f32_16x16x32_f16(a0, b3, af3, 0, 0, 0);
            ag0 = __builtin_amdgcn_mfma_f32_16x16x32_f16(a1, b0, ag0, 0, 0, 0);
            ag1 = __builtin_amdgcn_mfma_f32_16x16x32_f16(a1, b1, ag1, 0, 0, 0);
            ag2 = __builtin_amdgcn_mfma_f32_16x16x32_f16(a1, b2, ag2, 0, 0, 0);
            ag3 = __builtin_amdgcn_mfma_f32_16x16x32_f16(a1, b3, ag3, 0, 0, 0);
            ab0 = __builtin_amdgcn_mfma_f32_16x16x32_f16(a0, c0, ab0, 0, 0, 0);
            ab1 = __builtin_amdgcn_mfma_f32_16x16x32_f16(a0, c1, ab1, 0, 0, 0);
            ab2 = __builtin_amdgcn_mfma_f32_16x16x32_f16(a0, c2, ab2, 0, 0, 0);
            ab3 = __builtin_amdgcn_mfma_f32_16x16x32_f16(a0, c3, ab3, 0, 0, 0);
            ac0 = __builtin_amdgcn_mfma_f32_16x16x32_f16(a1, c0, ac0, 0, 0, 0);
            ac1 = __builtin_amdgcn_mfma_f32_16x16x32_f16(a1, c1, ac1, 0, 0, 0);
            ac2 = __builtin_amdgcn_mfma_f32_16x16x32_f16(a1, c2, ac2, 0, 0, 0);
            ac3 = __builtin_amdgcn_mfma_f32_16x16x32_f16(a1, c3, ac3, 0, 0, 0);
        }
    }
    f32x4 fa[2][4] = {{af0, af1, af2, af3}, {ag0, ag1, ag2, ag3}};
    f32x4 ba[2][4] = {{ab0, ab1, ab2, ab3}, {ac0, ac1, ac2, ac3}};
#pragma unroll
    for (int mi = 0; mi < 2; mi++) {
        int orow = m0 + wv * 32 + mi * 16 + lk * 4;
#pragma unroll
        for (int jn = 0; jn < 4; jn++) {
            int col = n0 + jn * 16 + lm;
            float bvf = biasf[col], bvb = biasb[col];
#pragma unroll
            for (int r = 0; r < 4; r++) {
                Cf[(size_t)(orow + r) * G4 + col] = fa[mi][jn][r] + bvf;
                Cb[(size_t)(orow + r) * G4 + col] = ba[mi][jn][r] + bvb;
            }
        }
    }
}

// ---- masked BiLSTM (r13 structure): o-gate in 128 KB LDS; g-gate in 32 VGPRs;
// i,f streamed 256 KB/step from L2. Output h stored f16 into hcat[w][512]
// (fwd dir -> cols 0..255, bwd -> 256..511); value == the f16 state hh.
__global__ __launch_bounds__(1024, 4) void k_lstm(const float* __restrict__ xs_f,
                                               const float* __restrict__ xs_b,
                                               const _Float16* __restrict__ wh_f,
                                               const _Float16* __restrict__ wh_b,
                                               const int* __restrict__ wlen,
                                               _Float16* __restrict__ hcat) {
    int b = blockIdx.x & 63, d = blockIdx.x >> 6;
    const float* xs = d ? xs_b : xs_f;
    const uint4* wp4 = (const uint4*)(d ? wh_b : wh_f);
    int len = wlen[b];
    __shared__ uint4 olds4[8192];                 // o-gate weights, 128 KB
    __shared__ _Float16 __align__(16) hh[256];    // f16 h state
    __shared__ float part[4][4][256];             // [s][gate][unit], 16 KB
    int tid = threadIdx.x;
    int j = tid & 255, s = tid >> 8;
    const uint4* pi = wp4 + (size_t)((s * 4 + 0) * 8) * 256 + j;   // i (streamed)
    const uint4* pf = wp4 + (size_t)((s * 4 + 1) * 8) * 256 + j;   // f (streamed)
    uint4 wg[8];                                   // g-gate resident (32 VGPRs)
    {
        const uint4* pg = wp4 + (size_t)((s * 4 + 2) * 8) * 256 + j;
        const uint4* po = wp4 + (size_t)((s * 4 + 3) * 8) * 256 + j;
#pragma unroll
        for (int k8 = 0; k8 < 8; k8++) {
            wg[k8] = pg[k8 * 256];
            olds4[k8 * 1024 + tid] = po[k8 * 256];
        }
    }
#pragma unroll
    for (int k8 = 0; k8 < 8; k8++) KEEPU4(wg[k8]);
    if (tid < 128) ((unsigned*)hh)[tid] = 0u;
    float c = 0.f;
    const uint4* hsh4 = (const uint4*)hh;
    __syncthreads();
    for (int ss = 0; ss < len; ++ss) {
        int t = d ? (len - 1 - ss) : ss;
        float xv0, xv1, xv2, xv3;
        if (tid < 256) {
            const float* xr = xs + (size_t)(b * TT + t) * G4;
            xv0 = xr[tid];
            xv1 = xr[256 + tid];
            xv2 = xr[512 + tid];
            xv3 = xr[768 + tid];
        }
        asm volatile("" : "+v"(pi), "+v"(pf));
        float a0 = 0.f, a1 = 0.f, a2 = 0.f, a3 = 0.f;
#pragma unroll
        for (int k8 = 0; k8 < 8; k8++) {
            uint4 h4 = hsh4[s * 8 + k8];                       // broadcast
            uint4 wi = pi[k8 * 256];
            uint4 wf = pf[k8 * 256];
            uint4 wo = olds4[k8 * 1024 + tid];
            a0 = dot8(wi, h4, a0);
            a1 = dot8(wf, h4, a1);
            a2 = dot8(wg[k8], h4, a2);
            a3 = dot8(wo, h4, a3);
        }
        part[s][0][j] = a0;
        part[s][1][j] = a1;
        part[s][2][j] = a2;
        part[s][3][j] = a3;
        __syncthreads();
        if (tid < 256) {
            float s0 = part[0][0][tid] + part[1][0][tid] + part[2][0][tid] + part[3][0][tid] + xv0;
            float s1 = part[0][1][tid] + part[1][1][tid] + part[2][1][tid] + part[3][1][tid] + xv1;
            float s2 = part[0][2][tid] + part[1][2][tid] + part[2][2][tid] + part[3][2][tid] + xv2;
            float s3 = part[0][3][tid] + part[1][3][tid] + part[2][3][tid] + part[3][3][tid] + xv3;
            float ig = sigm(s0), fg = sigm(s1), zg = tanhf(s2), og = sigm(s3);
            c = fg * c + ig * zg;
            float h = og * tanhf(c);
            _Float16 h16 = (_Float16)h;
            hh[tid] = h16;
            hcat[(size_t)(b * TT + t) * 512 + d * 256 + tid] = h16;
        }
        __syncthreads();
    }
}

// ---- projection via MFMA: feats[w][52] = hcat[w][0:512] . pw16[tag][0:512] + pb
// 256 blocks x 256 thr (4 waves); A tile 64x512 + full B 64x512 staged once
// (144 KB LDS, one barrier); 8 chunks x 2 ksteps x 4 n-frags = 64 mfma/wave.
__global__ __launch_bounds__(256) void k_projm(const _Float16* __restrict__ A,
                                               const _Float16* __restrict__ Bw,
                                               const float* __restrict__ pb,
                                               float* __restrict__ feats) {
    __shared__ __align__(16) _Float16 Al[8 * 64 * 72];
    __shared__ __align__(16) _Float16 Bl[8 * 64 * 72];
    int tid = threadIdx.x;
    int wv = tid >> 6, l = tid & 63;
    int lm = l & 15, lk = l >> 4;
    int m0 = blockIdx.x * 64;
#pragma unroll
    for (int q = 0; q < 16; q++) {
        int ch = tid + q * 256;           // 0..4095 uint4
        int r = ch >> 6;                  // row 0..63
        int rem = ch & 63;
        int cnk = rem >> 3, cc = rem & 7; // chunk, 16B-offset within chunk
        ((uint4*)Al)[(cnk * 64 + r) * 9 + cc] =
            *(const uint4*)&A[(size_t)(m0 + r) * 512 + cnk * 64 + cc * 8];
        ((uint4*)Bl)[(cnk * 64 + r) * 9 + cc] =
            *(const uint4*)&Bw[(size_t)r * 512 + cnk * 64 + cc * 8];
    }
    __syncthreads();
    f32x4 z = {0.f, 0.f, 0.f, 0.f};
    f32x4 ac0 = z, ac1 = z, ac2 = z, ac3 = z;
#pragma unroll
    for (int cnk = 0; cnk < 8; cnk++) {
#pragma unroll
        for (int ks = 0; ks < 2; ks++) {
            int kk = ks * 4 + lk;
            f16x8 a  = ((const f16x8*)Al)[(cnk * 64 + wv * 16 + lm) * 9 + kk];
            f16x8 b0 = ((const f16x8*)Bl)[(cnk * 64 +  0 + lm) * 9 + kk];
            f16x8 b1 = ((const f16x8*)Bl)[(cnk * 64 + 16 + lm) * 9 + kk];
            f16x8 b2 = ((const f16x8*)Bl)[(cnk * 64 + 32 + lm) * 9 + kk];
            f16x8 b3 = ((const f16x8*)Bl)[(cnk * 64 + 48 + lm) * 9 + kk];
            ac0 = __builtin_amdgcn_mfma_f32_16x16x32_f16(a, b0, ac0, 0, 0, 0);
            ac1 = __builtin_amdgcn_mfma_f32_16x16x32_f16(a, b1, ac1, 0, 0, 0);
            ac2 = __builtin_amdgcn_mfma_f32_16x16x32_f16(a, b2, ac2, 0, 0, 0);
            ac3 = __builtin_amdgcn_mfma_f32_16x16x32_f16(a, b3, ac3, 0, 0, 0);
        }
    }
    f32x4 accs[4] = {ac0, ac1, ac2, ac3};
    int orow = m0 + wv * 16 + lk * 4;     // C/D: col=lane&15, row=(lane>>4)*4+r
#pragma unroll
    for (int jn = 0; jn < 4; jn++) {
        int col = jn * 16 + lm;
        if (col < NTAG) {
            float bv = pb[col];
#pragma unroll
            for (int r = 0; r < 4; r++)
                feats[(size_t)(orow + r) * NTAG + col] = accs[jn][r] + bv;
        }
    }
}

// ---- CRF: 128 single-wave blocks. Blocks 0..63: forward + gold + loss
// (+ last-block total). Blocks 64..127: viterbi + backtrace.
__global__ __launch_bounds__(64) void k_crf(const float* __restrict__ feats,
                                            const float* __restrict__ trans,
                                            const int* __restrict__ wlen,
                                            const int* __restrict__ blabel,
                                            float* __restrict__ lossb,
                                            float* __restrict__ outtags,
                                            unsigned* __restrict__ ctr,
                                            float* __restrict__ out) {
    __shared__ float Tm[NTAG * NTAG];
    __shared__ float st[NTAG];
    __shared__ unsigned char bp[TT - 1][NTAG];
    int bid = blockIdx.x;
    int b = bid & 63;
    bool vit = bid >= BB;
    int j = threadIdx.x;
    for (int s = j; s < NTAG * NTAG; s += 64) Tm[s] = trans[s];
    __builtin_amdgcn_wave_barrier();
    int len = wlen[b];
    const float* fb = feats + (size_t)b * TT * NTAG;
    if (j < NTAG) st[j] = fb[j] + Tm[TSTART * NTAG + j];
    __builtin_amdgcn_wave_barrier();
    if (!vit) {
        float frow = (j < NTAG && len > 1) ? fb[NTAG + j] : 0.f;
        for (int t = 1; t < len; t++) {
            float frow_nxt = (j < NTAG && t + 1 < len) ? fb[(size_t)(t + 1) * NTAG + j] : 0.f;
            float anew = 0.f;
            if (j < NTAG) {
                float ma = -1e30f, mb = -1e30f, mc = -1e30f, md = -1e30f;
                for (int i = 0; i < 13; i++) {
                    ma = fmaxf(ma, st[i]      + Tm[i * NTAG + j]);
                    mb = fmaxf(mb, st[i + 13] + Tm[(i + 13) * NTAG + j]);
                    mc = fmaxf(mc, st[i + 26] + Tm[(i + 26) * NTAG + j]);
                    md = fmaxf(md, st[i + 39] + Tm[(i + 39) * NTAG + j]);
                }
                float m1 = fmaxf(fmaxf(ma, mb), fmaxf(mc, md));
                float sa = 0.f, sb = 0.f, sc = 0.f, sd = 0.f;
                for (int i = 0; i < 13; i++) {
                    sa += expf(st[i]      + Tm[i * NTAG + j] - m1);
                    sb += expf(st[i + 13] + Tm[(i + 13) * NTAG + j] - m1);
                    sc += expf(st[i + 26] + Tm[(i + 26) * NTAG + j] - m1);
                    sd += expf(st[i + 39] + Tm[(i + 39) * NTAG + j] - m1);
                }
                anew = m1 + logf((sa + sb) + (sc + sd)) + frow;
            }
            __builtin_amdgcn_wave_barrier();
            if (j < NTAG) st[j] = anew;
            __builtin_amdgcn_wave_barrier();
            frow = frow_nxt;
        }
        float red = (j < NTAG) ? st[j] + Tm[j * NTAG + TSTOP] : -1e30f;
        float m1 = red;
#pragma unroll
        for (int m = 32; m; m >>= 1) m1 = fmaxf(m1, __shfl_xor(m1, m));
        float e = (j < NTAG) ? expf(red - m1) : 0.f;
        float ssum = e;
#pragma unroll
        for (int m = 32; m; m >>= 1) ssum += __shfl_xor(ssum, m);
        const int* lab = blabel + b * TT;
        float gpart = 0.f;
        for (int t = 1 + j; t < len; t += 64)
            gpart += Tm[lab[t - 1] * NTAG + lab[t]] + fb[(size_t)t * NTAG + lab[t]];
#pragma unroll
        for (int m = 32; m; m >>= 1) gpart += __shfl_xor(gpart, m);
        if (j == 0) {
            float Zg = m1 + logf(ssum);
            float goldv = Tm[TSTART * NTAG + lab[0]] + fb[lab[0]] + gpart
                        + Tm[lab[len - 1] * NTAG + TSTOP];
            lossb[b] = Zg - goldv;
            __threadfence();
            unsigned old = atomicAdd(ctr, 1u);
            if (old == BB - 1) {
                __threadfence();
                float stot = 0.f;
                for (int i = 0; i < BB; i++) stot += lossb[i];
                out[0] = stot;
            }
        }
    } else {
        float frow = (j < NTAG && len > 1) ? fb[NTAG + j] : 0.f;
        for (int t = 1; t < len; t++) {
            float frow_nxt = (j < NTAG && t + 1 < len) ? fb[(size_t)(t + 1) * NTAG + j] : 0.f;
            float vnew = 0.f;
            int arg = 0;
            if (j < NTAG) {
                float va = -1e30f, vb = -1e30f, vc = -1e30f, vd = -1e30f;
                int ia = 0, ib = 13, ic = 26, id2 = 39;
                for (int i = 0; i < 13; i++) {
                    float s0 = st[i]      + Tm[i * NTAG + j];        if (s0 > va) { va = s0; ia = i; }
                    float s1 = st[i + 13] + Tm[(i + 13) * NTAG + j]; if (s1 > vb) { vb = s1; ib = i + 13; }
                    float s2 = st[i + 26] + Tm[(i + 26) * NTAG + j]; if (s2 > vc) { vc = s2; ic = i + 26; }
                    float s3 = st[i + 39] + Tm[(i + 39) * NTAG + j]; if (s3 > vd) { vd = s3; id2 = i + 39; }
                }
                float vm = va; arg = ia;
                if (vb > vm) { vm = vb; arg = ib; }
                if (vc > vm) { vm = vc; arg = ic; }
                if (vd > vm) { vm = vd; arg = id2; }
                vnew = vm + frow;
            }
            __builtin_amdgcn_wave_barrier();
            if (j < NTAG) {
                st[j] = vnew;
                bp[t - 1][j] = (unsigned char)arg;
            }
            __builtin_amdgcn_wave_barrier();
            frow = frow_nxt;
        }
        if (j == 0) {
            int best = 0;
            float vm = st[0] + Tm[0 * NTAG + TSTOP];
            for (int i = 1; i < NTAG; i++) {
                float v = st[i] + Tm[i * NTAG + TSTOP];
                if (v > vm) { vm = v; best = i; }
            }
            float* ot = outtags + (size_t)b * TT;
            int tag = best;
            ot[len - 1] = (float)tag;
            for (int t = len - 2; t >= 0; t--) {
                tag = bp[t][tag];
                ot[t] = (float)tag;
            }
            for (int t = len; t < TT; t++) ot[t] = 0.f;
        }
    }
}

extern "C" void kernel_launch(void* const* d_in, const int* in_sizes, int n_in,
                              void* d_out, int out_size, void* d_ws, size_t ws_size,
                              hipStream_t stream) {
    const int* batch_word     = (const int*)d_in[0];
    const int* batch_features = (const int*)d_in[1];
    const int* batch_wordlen  = (const int*)d_in[2];
    const int* batch_char     = (const int*)d_in[3];
    const int* batch_recover  = (const int*)d_in[5];
    const int* batch_label    = (const int*)d_in[7];
    const float* char_emb = (const float*)d_in[8];
    const float* conv_w   = (const float*)d_in[9];
    const float* conv_b   = (const float*)d_in[10];
    const float* word_emb = (const float*)d_in[11];
    const float* feat_emb = (const float*)d_in[12];
    const float* w_ih_f   = (const float*)d_in[13];
    const float* w_hh_f   = (const float*)d_in[14];
    const float* b_f      = (const float*)d_in[15];
    const float* w_ih_b   = (const float*)d_in[16];
    const float* w_hh_b   = (const float*)d_in[17];
    const float* b_b      = (const float*)d_in[18];
    const float* proj_w   = (const float*)d_in[19];
    const float* proj_b   = (const float*)d_in[20];
    const float* trans    = (const float*)d_in[21];

    char* ws = (char*)d_ws;
    float* pooled   = (float*)(ws + OFF_POOL);
    _Float16* xh    = (_Float16*)(ws + OFF_XH);
    _Float16* wh16f = (_Float16*)(ws + OFF_W16F);
    _Float16* wh16b = (_Float16*)(ws + OFF_W16B);
    _Float16* pw16  = (_Float16*)(ws + OFF_PW16);
    _Float16* hcat  = (_Float16*)(ws + OFF_HCAT);
    float* xs_f   = (float*)(ws + OFF_XSF);
    float* xs_b   = (float*)(ws + OFF_XSB);
    float* feats  = (float*)(ws + OFF_FEATS);
    _Float16* wh_f = (_Float16*)(ws + OFF_WPF);
    _Float16* wh_b = (_Float16*)(ws + OFF_WPB);
    float* lossb  = (float*)(ws + OFF_LOSSB);
    unsigned* ctr = (unsigned*)(ws + OFF_CTR);

    k_front<<<CHARCNN_BLOCKS + PREP_BLOCKS, 256, 0, stream>>>(
        batch_char, char_emb, conv_w, conv_b, pooled,
        w_hh_f, w_hh_b, w_ih_f, w_ih_b, proj_w,
        wh_f, wh_b, wh16f, wh16b, pw16, ctr);
    k_concat<<<(BB * TT) / 8, 256, 0, stream>>>(batch_word, batch_features, batch_recover,
                                                word_emb, feat_emb, pooled, xh);
    k_gemm16b<<<dim3(G4 / 64, (BB * TT) / 128), 256, 0, stream>>>(xh, wh16f, wh16b,
                                                                  b_f, b_b, xs_f, xs_b);
    k_lstm<<<128, 1024, 0, stream>>>(xs_f, xs_b, wh_f, wh_b, batch_wordlen, hcat);
    k_projm<<<(BB * TT) / 64, 256, 0, stream>>>(hcat, pw16, proj_b, feats);
    k_crf<<<2 * BB, 64, 0, stream>>>(feats, trans, batch_wordlen, batch_label,
                                     lossb, (float*)d_out + 1, ctr, (float*)d_out);
}

// Round 18
// 1364.140 us; speedup vs baseline: 1.4018x; 1.0992x over previous
//
#include <hip/hip_runtime.h>
#include <hip/hip_bf16.h>
#include <math.h>

#define BB 64
#define TT 256
#define LCH 16
#define DC 50
#define CHN 100
#define DW 300
#define DF 20
#define HID 256
#define G4 1024
#define INDIM 420
#define KPAD 448
#define NTAG 52
#define TSTART 50
#define TSTOP 51

// ------------------- workspace layout (bytes) -------------------
static constexpr size_t OFF_POOL  = 0;                       // 6,553,600 (dead after concat)
static constexpr size_t OFF_XH    = 6553600;                 // 14,680,064 f16 -> 21,233,664 (dead after gemm)
static constexpr size_t OFF_W16F  = 21233664;                // 917,504 f16 w_ih fwd
static constexpr size_t OFF_W16B  = 22151168;                // -> 23,068,672
static constexpr size_t OFF_PW16  = 23068672;                // 65,536 f16 proj_w -> 23,134,208
static constexpr size_t OFF_HCAT  = 0;                       // 16,777,216 f16 [16384][512] (lstm out)
static constexpr size_t OFF_XSF   = 34078720;                // 67,108,864
static constexpr size_t OFF_XSB   = 101187584;               // -> 168,296,448
static constexpr size_t OFF_FEATS = 168296448;               // 3,407,872 -> 171,704,320
static constexpr size_t OFF_WPF   = 171704320;               // 512 KB fp16 packed W_hh fwd
static constexpr size_t OFF_WPB   = 172752896;               // 512 KB fp16 packed W_hh bwd
static constexpr size_t OFF_LOSSB = 173801472;               // 256 B (64 floats)
static constexpr size_t OFF_CTR   = 173801728;               // 4 B (unsigned counter)

typedef _Float16 v2h __attribute__((ext_vector_type(2)));
typedef _Float16 f16x8 __attribute__((ext_vector_type(8)));
typedef float f32x4 __attribute__((ext_vector_type(4)));
union UH2 { unsigned u; v2h h; };
__device__ __forceinline__ float fdot2u(unsigned a, unsigned b, float c) {
    UH2 x, y; x.u = a; y.u = b;
    return __builtin_amdgcn_fdot2(x.h, y.h, c, false);
}
__device__ __forceinline__ float dot8(uint4 w, uint4 h, float acc) {
    acc = fdot2u(w.x, h.x, acc);
    acc = fdot2u(w.y, h.y, acc);
    acc = fdot2u(w.z, h.z, acc);
    acc = fdot2u(w.w, h.w, acc);
    return acc;
}
#define KEEPU4(v) asm volatile("" : "+v"((v).x), "+v"((v).y), "+v"((v).z), "+v"((v).w))

__device__ __forceinline__ float sigm(float x) { return 1.0f / (1.0f + expf(-x)); }

// ================= fused front kernel: charcnn (blocks 0..2047) +
//       prep pack/cvt incl. proj_w f16 (blocks 2048..) + counter zero ==========
#define CHARCNN_BLOCKS 2048
#define PREP_BLOCKS 5760          // ceil(1474560 / 256)

__device__ __forceinline__ void packh_one(const float* __restrict__ w,
                                          _Float16* __restrict__ wph, int e) {
    int r  = e & 7;
    int j  = (e >> 3) & 255;
    int k8 = (e >> 11) & 7;
    int g  = (e >> 14) & 3;
    int s  = (e >> 16) & 3;
    wph[e] = (_Float16)w[(g * 256 + j) * HID + (s * 64 + k8 * 8 + r)];
}
__device__ __forceinline__ void cvtw_one(const float* __restrict__ w,
                                         _Float16* __restrict__ wh, int e) {
    int row = e / KPAD, k = e % KPAD;
    wh[e] = (k < INDIM) ? (_Float16)w[row * INDIM + k] : (_Float16)0.f;
}

__global__ __launch_bounds__(256) void k_front(const int* __restrict__ bchar,
                                               const float* __restrict__ cemb,
                                               const float* __restrict__ cw,
                                               const float* __restrict__ cb,
                                               float* __restrict__ pooled,
                                               const float* __restrict__ whf,
                                               const float* __restrict__ whb,
                                               const float* __restrict__ wihf,
                                               const float* __restrict__ wihb,
                                               const float* __restrict__ pw,
                                               _Float16* __restrict__ wpf,
                                               _Float16* __restrict__ wpb,
                                               _Float16* __restrict__ wh16f,
                                               _Float16* __restrict__ wh16b,
                                               _Float16* __restrict__ pw16,
                                               unsigned* __restrict__ ctr) {
    __shared__ float cwsh[150][100];   // [d*3+q][c], 60 KB
    __shared__ float ET[2][DC][20];
    __shared__ int ids[2][LCH];
    int tid = threadIdx.x;
    if (blockIdx.x >= CHARCNN_BLOCKS) {
        // ---- prep body ----
        int e = (blockIdx.x - CHARCNN_BLOCKS) * 256 + tid;
        if (e == 0) *ctr = 0u;                       // zero last-block counter
        if (e < 262144)                packh_one(whf, wpf, e);
        else if (e < 524288)           packh_one(whb, wpb, e - 262144);
        else if (e < 983040)           cvtw_one(wihf, wh16f, e - 524288);
        else if (e < 1441792)          cvtw_one(wihb, wh16b, e - 983040);
        else if (e < 1474560) {
            int p = e - 1441792;                     // [64][512] f16, rows >= 52 zero
            int row = p >> 9;
            pw16[p] = (row < NTAG) ? (_Float16)pw[row * 512 + (p & 511)] : (_Float16)0.f;
        }
        return;
    }
    // ---- charcnn body: 8 words/block; cwsh + ET gathers coalesced ----
    int wbase = blockIdx.x * 8;
    for (int i = tid; i < 15000; i += 256) {
        int c = i / 150, row = i % 150;
        cwsh[row][c] = cw[i];
    }
    int half = tid >> 7, c = tid & 127;
    float bcv = (c < CHN) ? cb[c] : 0.f;
    for (int g = 0; g < 8; g += 2) {
        __syncthreads();
        if (tid < 32) ids[tid >> 4][tid & 15] = bchar[(wbase + g + (tid >> 4)) * LCH + (tid & 15)];
        __syncthreads();
        // d-fastest decomposition: 50 consecutive lanes read one cemb row coalesced
        for (int s2 = tid; s2 < 2 * DC * 18; s2 += 256) {
            int w2 = s2 / 900, rem = s2 % 900;
            int l = rem / DC, d = rem % DC;
            float v = 0.f;
            if (l >= 1 && l <= 16) v = cemb[ids[w2][l - 1] * DC + d];
            ET[w2][d][l] = v;
        }
        __syncthreads();
        if (c < CHN) {
            float acc[16];
#pragma unroll
            for (int l = 0; l < 16; l++) acc[l] = 0.f;
            for (int d = 0; d < DC; d++) {
                float e[18];
                float4 t0 = *(const float4*)&ET[half][d][0];
                float4 t1 = *(const float4*)&ET[half][d][4];
                float4 t2 = *(const float4*)&ET[half][d][8];
                float4 t3 = *(const float4*)&ET[half][d][12];
                e[0]=t0.x; e[1]=t0.y; e[2]=t0.z; e[3]=t0.w;
                e[4]=t1.x; e[5]=t1.y; e[6]=t1.z; e[7]=t1.w;
                e[8]=t2.x; e[9]=t2.y; e[10]=t2.z; e[11]=t2.w;
                e[12]=t3.x; e[13]=t3.y; e[14]=t3.z; e[15]=t3.w;
                e[16]=ET[half][d][16]; e[17]=ET[half][d][17];
                float w0 = cwsh[d * 3 + 0][c];
                float w1 = cwsh[d * 3 + 1][c];
                float w2 = cwsh[d * 3 + 2][c];
#pragma unroll
                for (int l = 0; l < 16; l++)
                    acc[l] += w0 * e[l] + w1 * e[l + 1] + w2 * e[l + 2];
            }
            float m = acc[0];
#pragma unroll
            for (int l = 1; l < 16; l++) m = fmaxf(m, acc[l]);
            pooled[(wbase + g + half) * CHN + c] = m + bcv;
        }
    }
}

// ---- assemble xh[16384][448] f16; 8 words per block, 256 threads
__global__ __launch_bounds__(256) void k_concat(const int* __restrict__ word,
                                                const int* __restrict__ featsidx,
                                                const int* __restrict__ recover,
                                                const float* __restrict__ wemb,
                                                const float* __restrict__ femb,
                                                const float* __restrict__ pooled,
                                                _Float16* __restrict__ xh) {
    int tid = threadIdx.x;
    for (int wi = 0; wi < 8; wi++) {
        int w = blockIdx.x * 8 + wi;
        int b = w >> 8;
        int wid = word[w];
        _Float16* xr = xh + (size_t)w * KPAD;
        for (int c = tid; c < DW; c += 256) xr[c] = (_Float16)wemb[(size_t)wid * DW + c];
        int rc = recover[w];
        if (tid < CHN) xr[DW + tid] = (_Float16)pooled[rc * CHN + tid];
        if (tid < DF)  xr[DW + CHN + tid] = (_Float16)femb[featsidx[b] * DF + tid];
        if (tid >= 100 && tid < 100 + (KPAD - INDIM)) xr[INDIM + (tid - 100)] = (_Float16)0.f;
    }
}

// ---- fused f16 MFMA GEMM for BOTH directions, LDS-staged, reg-prefetched:
// global loads for tile k0 are issued BEFORE the first barrier so their L2
// latency overlaps the previous iteration's MFMAs.
__global__ __launch_bounds__(256, 4) void k_gemm16b(const _Float16* __restrict__ A,
                                                    const _Float16* __restrict__ Bf,
                                                    const _Float16* __restrict__ Bb,
                                                    const float* __restrict__ biasf,
                                                    const float* __restrict__ biasb,
                                                    float* __restrict__ Cf,
                                                    float* __restrict__ Cb) {
    __shared__ __align__(16) _Float16 Asl[128 * 72];
    __shared__ __align__(16) _Float16 Bfl[64 * 72];
    __shared__ __align__(16) _Float16 Bbl[64 * 72];
    int tid = threadIdx.x;
    int wv = tid >> 6, l = tid & 63;
    int lm = l & 15, lk = l >> 4;
    int n0 = blockIdx.x * 64, m0 = blockIdx.y * 128;
    f32x4 z = {0.f, 0.f, 0.f, 0.f};
    f32x4 af0 = z, af1 = z, af2 = z, af3 = z;
    f32x4 ag0 = z, ag1 = z, ag2 = z, ag3 = z;
    f32x4 ab0 = z, ab1 = z, ab2 = z, ab3 = z;
    f32x4 ac0 = z, ac1 = z, ac2 = z, ac3 = z;
    // address decomposition for staging (constant per thread)
    int ra_[4], rca_[4];
#pragma unroll
    for (int q = 0; q < 4; q++) { int ch = tid + q * 256; ra_[q] = ch >> 3; rca_[q] = ch & 7; }
    int rb_[2], rcb_[2];
#pragma unroll
    for (int q = 0; q < 2; q++) { int ch = tid + q * 256; rb_[q] = ch >> 3; rcb_[q] = ch & 7; }
    for (int k0 = 0; k0 < KPAD; k0 += 64) {
        // ---- issue global loads into regs (overlaps previous MFMAs) ----
        uint4 va[4], vbf[2], vbb[2];
#pragma unroll
        for (int q = 0; q < 4; q++)
            va[q] = *(const uint4*)&A[(size_t)(m0 + ra_[q]) * KPAD + k0 + rca_[q] * 8];
#pragma unroll
        for (int q = 0; q < 2; q++) {
            vbf[q] = *(const uint4*)&Bf[(size_t)(n0 + rb_[q]) * KPAD + k0 + rcb_[q] * 8];
            vbb[q] = *(const uint4*)&Bb[(size_t)(n0 + rb_[q]) * KPAD + k0 + rcb_[q] * 8];
        }
        __syncthreads();                  // previous iter's ds_reads complete
#pragma unroll
        for (int q = 0; q < 4; q++)
            ((uint4*)Asl)[ra_[q] * 9 + rca_[q]] = va[q];
#pragma unroll
        for (int q = 0; q < 2; q++) {
            ((uint4*)Bfl)[rb_[q] * 9 + rcb_[q]] = vbf[q];
            ((uint4*)Bbl)[rb_[q] * 9 + rcb_[q]] = vbb[q];
        }
        __syncthreads();
#pragma unroll
        for (int kstep = 0; kstep < 2; kstep++) {
            int kk = kstep * 4 + lk;
            f16x8 a0 = ((const f16x8*)Asl)[(wv * 32 + lm) * 9 + kk];
            f16x8 a1 = ((const f16x8*)Asl)[(wv * 32 + 16 + lm) * 9 + kk];
            f16x8 b0 = ((const f16x8*)Bfl)[(0 * 16 + lm) * 9 + kk];
            f16x8 b1 = ((const f16x8*)Bfl)[(1 * 16 + lm) * 9 + kk];
            f16x8 b2 = ((const f16x8*)Bfl)[(2 * 16 + lm) * 9 + kk];
            f16x8 b3 = ((const f16x8*)Bfl)[(3 * 16 + lm) * 9 + kk];
            f16x8 c0 = ((const f16x8*)Bbl)[(0 * 16 + lm) * 9 + kk];
            f16x8 c1 = ((const f16x8*)Bbl)[(1 * 16 + lm) * 9 + kk];
            f16x8 c2 = ((const f16x8*)Bbl)[(2 * 16 + lm) * 9 + kk];
            f16x8 c3 = ((const f16x8*)Bbl)[(3 * 16 + lm) * 9 + kk];
            af0 = __builtin_amdgcn_mfma_f32_16x16x32_f16(a0, b0, af0, 0, 0, 0);
            af1 = __builtin_amdgcn_mfma_f32_16x16x32_f16(a0, b1, af1, 0, 0, 0);
            af2 = __builtin_amdgcn_mfma_f32_16x16x32_f16(a0, b2, af2, 0, 0, 0);
            af3 = __builtin_amdgcn_mfma_f32_16x16x32_f16(a0, b3, af3, 0, 0, 0);
            ag0 = __builtin_amdgcn_mfma_f32_16x16x32_f16(a1, b0, ag0, 0, 0, 0);
            ag1 = __builtin_amdgcn_mfma_f32_16x16x32_f16(a1, b1, ag1, 0, 0, 0);
            ag2 = __builtin_amdgcn_mfma_f32_16x16x32_f16(a1, b2, ag2, 0, 0, 0);
            ag3 = __builtin_amdgcn_mfma_f32_16x16x32_f16(a1, b3, ag3, 0, 0, 0);
            ab0 = __builtin_amdgcn_mfma_f32_16x16x32_f16(a0, c0, ab0, 0, 0, 0);
            ab1 = __builtin_amdgcn_mfma_f32_16x16x32_f16(a0, c1, ab1, 0, 0, 0);
            ab2 = __builtin_amdgcn_mfma_f32_16x16x32_f16(a0, c2, ab2, 0, 0, 0);
            ab3 = __builtin_amdgcn_mfma_f32_16x16x32_f16(a0, c3, ab3, 0, 0, 0);
            ac0 = __builtin_amdgcn_mfma_f32_16x16x32_f16(a1, c0, ac0, 0, 0, 0);
            ac1 = __builtin_amdgcn_mfma_f32_16x16x32_f16(a1, c1, ac1, 0, 0, 0);
            ac2 = __builtin_amdgcn_mfma_f32_16x16x32_f16(a1, c2, ac2, 0, 0, 0);
            ac3 = __builtin_amdgcn_mfma_f32_16x16x32_f16(a1, c3, ac3, 0, 0, 0);
        }
    }
    f32x4 fa[2][4] = {{af0, af1, af2, af3}, {ag0, ag1, ag2, ag3}};
    f32x4 ba[2][4] = {{ab0, ab1, ab2, ab3}, {ac0, ac1, ac2, ac3}};
#pragma unroll
    for (int mi = 0; mi < 2; mi++) {
        int orow = m0 + wv * 32 + mi * 16 + lk * 4;
#pragma unroll
        for (int jn = 0; jn < 4; jn++) {
            int col = n0 + jn * 16 + lm;
            float bvf = biasf[col], bvb = biasb[col];
#pragma unroll
            for (int r = 0; r < 4; r++) {
                Cf[(size_t)(orow + r) * G4 + col] = fa[mi][jn][r] + bvf;
                Cb[(size_t)(orow + r) * G4 + col] = ba[mi][jn][r] + bvb;
            }
        }
    }
}

// ---- masked BiLSTM (r13 structure): o-gate in 128 KB LDS; g-gate in 32 VGPRs;
// i,f streamed 256 KB/step from L2. Output h stored f16 into hcat[w][512].
__global__ __launch_bounds__(1024, 4) void k_lstm(const float* __restrict__ xs_f,
                                               const float* __restrict__ xs_b,
                                               const _Float16* __restrict__ wh_f,
                                               const _Float16* __restrict__ wh_b,
                                               const int* __restrict__ wlen,
                                               _Float16* __restrict__ hcat) {
    int b = blockIdx.x & 63, d = blockIdx.x >> 6;
    const float* xs = d ? xs_b : xs_f;
    const uint4* wp4 = (const uint4*)(d ? wh_b : wh_f);
    int len = wlen[b];
    __shared__ uint4 olds4[8192];                 // o-gate weights, 128 KB
    __shared__ _Float16 __align__(16) hh[256];    // f16 h state
    __shared__ float part[4][4][256];             // [s][gate][unit], 16 KB
    int tid = threadIdx.x;
    int j = tid & 255, s = tid >> 8;
    const uint4* pi = wp4 + (size_t)((s * 4 + 0) * 8) * 256 + j;   // i (streamed)
    const uint4* pf = wp4 + (size_t)((s * 4 + 1) * 8) * 256 + j;   // f (streamed)
    uint4 wg[8];                                   // g-gate resident (32 VGPRs)
    {
        const uint4* pg = wp4 + (size_t)((s * 4 + 2) * 8) * 256 + j;
        const uint4* po = wp4 + (size_t)((s * 4 + 3) * 8) * 256 + j;
#pragma unroll
        for (int k8 = 0; k8 < 8; k8++) {
            wg[k8] = pg[k8 * 256];
            olds4[k8 * 1024 + tid] = po[k8 * 256];
        }
    }
#pragma unroll
    for (int k8 = 0; k8 < 8; k8++) KEEPU4(wg[k8]);
    if (tid < 128) ((unsigned*)hh)[tid] = 0u;
    float c = 0.f;
    const uint4* hsh4 = (const uint4*)hh;
    __syncthreads();
    for (int ss = 0; ss < len; ++ss) {
        int t = d ? (len - 1 - ss) : ss;
        float xv0, xv1, xv2, xv3;
        if (tid < 256) {
            const float* xr = xs + (size_t)(b * TT + t) * G4;
            xv0 = xr[tid];
            xv1 = xr[256 + tid];
            xv2 = xr[512 + tid];
            xv3 = xr[768 + tid];
        }
        asm volatile("" : "+v"(pi), "+v"(pf));
        float a0 = 0.f, a1 = 0.f, a2 = 0.f, a3 = 0.f;
#pragma unroll
        for (int k8 = 0; k8 < 8; k8++) {
            uint4 h4 = hsh4[s * 8 + k8];                       // broadcast
            uint4 wi = pi[k8 * 256];
            uint4 wf = pf[k8 * 256];
            uint4 wo = olds4[k8 * 1024 + tid];
            a0 = dot8(wi, h4, a0);
            a1 = dot8(wf, h4, a1);
            a2 = dot8(wg[k8], h4, a2);
            a3 = dot8(wo, h4, a3);
        }
        part[s][0][j] = a0;
        part[s][1][j] = a1;
        part[s][2][j] = a2;
        part[s][3][j] = a3;
        __syncthreads();
        if (tid < 256) {
            float s0 = part[0][0][tid] + part[1][0][tid] + part[2][0][tid] + part[3][0][tid] + xv0;
            float s1 = part[0][1][tid] + part[1][1][tid] + part[2][1][tid] + part[3][1][tid] + xv1;
            float s2 = part[0][2][tid] + part[1][2][tid] + part[2][2][tid] + part[3][2][tid] + xv2;
            float s3 = part[0][3][tid] + part[1][3][tid] + part[2][3][tid] + part[3][3][tid] + xv3;
            float ig = sigm(s0), fg = sigm(s1), zg = tanhf(s2), og = sigm(s3);
            c = fg * c + ig * zg;
            float h = og * tanhf(c);
            _Float16 h16 = (_Float16)h;
            hh[tid] = h16;
            hcat[(size_t)(b * TT + t) * 512 + d * 256 + tid] = h16;
        }
        __syncthreads();
    }
}

// ---- projection via MFMA: feats[w][52] = hcat[w][0:512] . pw16[tag][0:512] + pb
__global__ __launch_bounds__(256) void k_projm(const _Float16* __restrict__ A,
                                               const _Float16* __restrict__ Bw,
                                               const float* __restrict__ pb,
                                               float* __restrict__ feats) {
    __shared__ __align__(16) _Float16 Al[8 * 64 * 72];
    __shared__ __align__(16) _Float16 Bl[8 * 64 * 72];
    int tid = threadIdx.x;
    int wv = tid >> 6, l = tid & 63;
    int lm = l & 15, lk = l >> 4;
    int m0 = blockIdx.x * 64;
#pragma unroll
    for (int q = 0; q < 16; q++) {
        int ch = tid + q * 256;           // 0..4095 uint4
        int r = ch >> 6;                  // row 0..63
        int rem = ch & 63;
        int cnk = rem >> 3, cc = rem & 7;
        ((uint4*)Al)[(cnk * 64 + r) * 9 + cc] =
            *(const uint4*)&A[(size_t)(m0 + r) * 512 + cnk * 64 + cc * 8];
        ((uint4*)Bl)[(cnk * 64 + r) * 9 + cc] =
            *(const uint4*)&Bw[(size_t)r * 512 + cnk * 64 + cc * 8];
    }
    __syncthreads();
    f32x4 z = {0.f, 0.f, 0.f, 0.f};
    f32x4 ac0 = z, ac1 = z, ac2 = z, ac3 = z;
#pragma unroll
    for (int cnk = 0; cnk < 8; cnk++) {
#pragma unroll
        for (int ks = 0; ks < 2; ks++) {
            int kk = ks * 4 + lk;
            f16x8 a  = ((const f16x8*)Al)[(cnk * 64 + wv * 16 + lm) * 9 + kk];
            f16x8 b0 = ((const f16x8*)Bl)[(cnk * 64 +  0 + lm) * 9 + kk];
            f16x8 b1 = ((const f16x8*)Bl)[(cnk * 64 + 16 + lm) * 9 + kk];
            f16x8 b2 = ((const f16x8*)Bl)[(cnk * 64 + 32 + lm) * 9 + kk];
            f16x8 b3 = ((const f16x8*)Bl)[(cnk * 64 + 48 + lm) * 9 + kk];
            ac0 = __builtin_amdgcn_mfma_f32_16x16x32_f16(a, b0, ac0, 0, 0, 0);
            ac1 = __builtin_amdgcn_mfma_f32_16x16x32_f16(a, b1, ac1, 0, 0, 0);
            ac2 = __builtin_amdgcn_mfma_f32_16x16x32_f16(a, b2, ac2, 0, 0, 0);
            ac3 = __builtin_amdgcn_mfma_f32_16x16x32_f16(a, b3, ac3, 0, 0, 0);
        }
    }
    f32x4 accs[4] = {ac0, ac1, ac2, ac3};
    int orow = m0 + wv * 16 + lk * 4;
#pragma unroll
    for (int jn = 0; jn < 4; jn++) {
        int col = jn * 16 + lm;
        if (col < NTAG) {
            float bv = pb[col];
#pragma unroll
            for (int r = 0; r < 4; r++)
                feats[(size_t)(orow + r) * NTAG + col] = accs[jn][r] + bv;
        }
    }
}

// ---- CRF: 128 single-wave blocks; fast-math exp/log (Viterbi path exact).
__global__ __launch_bounds__(64) void k_crf(const float* __restrict__ feats,
                                            const float* __restrict__ trans,
                                            const int* __restrict__ wlen,
                                            const int* __restrict__ blabel,
                                            float* __restrict__ lossb,
                                            float* __restrict__ outtags,
                                            unsigned* __restrict__ ctr,
                                            float* __restrict__ out) {
    __shared__ float Tm[NTAG * NTAG];
    __shared__ float st[NTAG];
    __shared__ unsigned char bp[TT - 1][NTAG];
    int bid = blockIdx.x;
    int b = bid & 63;
    bool vit = bid >= BB;
    int j = threadIdx.x;
    for (int s = j; s < NTAG * NTAG; s += 64) Tm[s] = trans[s];
    __builtin_amdgcn_wave_barrier();
    int len = wlen[b];
    const float* fb = feats + (size_t)b * TT * NTAG;
    if (j < NTAG) st[j] = fb[j] + Tm[TSTART * NTAG + j];
    __builtin_amdgcn_wave_barrier();
    if (!vit) {
        float frow = (j < NTAG && len > 1) ? fb[NTAG + j] : 0.f;
        for (int t = 1; t < len; t++) {
            float frow_nxt = (j < NTAG && t + 1 < len) ? fb[(size_t)(t + 1) * NTAG + j] : 0.f;
            float anew = 0.f;
            if (j < NTAG) {
                float ma = -1e30f, mb = -1e30f, mc = -1e30f, md = -1e30f;
                for (int i = 0; i < 13; i++) {
                    ma = fmaxf(ma, st[i]      + Tm[i * NTAG + j]);
                    mb = fmaxf(mb, st[i + 13] + Tm[(i + 13) * NTAG + j]);
                    mc = fmaxf(mc, st[i + 26] + Tm[(i + 26) * NTAG + j]);
                    md = fmaxf(md, st[i + 39] + Tm[(i + 39) * NTAG + j]);
                }
                float m1 = fmaxf(fmaxf(ma, mb), fmaxf(mc, md));
                float sa = 0.f, sb = 0.f, sc = 0.f, sd = 0.f;
                for (int i = 0; i < 13; i++) {
                    sa += __expf(st[i]      + Tm[i * NTAG + j] - m1);
                    sb += __expf(st[i + 13] + Tm[(i + 13) * NTAG + j] - m1);
                    sc += __expf(st[i + 26] + Tm[(i + 26) * NTAG + j] - m1);
                    sd += __expf(st[i + 39] + Tm[(i + 39) * NTAG + j] - m1);
                }
                anew = m1 + __logf((sa + sb) + (sc + sd)) + frow;
            }
            __builtin_amdgcn_wave_barrier();
            if (j < NTAG) st[j] = anew;
            __builtin_amdgcn_wave_barrier();
            frow = frow_nxt;
        }
        float red = (j < NTAG) ? st[j] + Tm[j * NTAG + TSTOP] : -1e30f;
        float m1 = red;
#pragma unroll
        for (int m = 32; m; m >>= 1) m1 = fmaxf(m1, __shfl_xor(m1, m));
        float e = (j < NTAG) ? __expf(red - m1) : 0.f;
        float ssum = e;
#pragma unroll
        for (int m = 32; m; m >>= 1) ssum += __shfl_xor(ssum, m);
        const int* lab = blabel + b * TT;
        float gpart = 0.f;
        for (int t = 1 + j; t < len; t += 64)
            gpart += Tm[lab[t - 1] * NTAG + lab[t]] + fb[(size_t)t * NTAG + lab[t]];
#pragma unroll
        for (int m = 32; m; m >>= 1) gpart += __shfl_xor(gpart, m);
        if (j == 0) {
            float Zg = m1 + __logf(ssum);
            float goldv = Tm[TSTART * NTAG + lab[0]] + fb[lab[0]] + gpart
                        + Tm[lab[len - 1] * NTAG + TSTOP];
            lossb[b] = Zg - goldv;
            __threadfence();
            unsigned old = atomicAdd(ctr, 1u);
            if (old == BB - 1) {
                __threadfence();
                float stot = 0.f;
                for (int i = 0; i < BB; i++) stot += lossb[i];
                out[0] = stot;
            }
        }
    } else {
        float frow = (j < NTAG && len > 1) ? fb[NTAG + j] : 0.f;
        for (int t = 1; t < len; t++) {
            float frow_nxt = (j < NTAG && t + 1 < len) ? fb[(size_t)(t + 1) * NTAG + j] : 0.f;
            float vnew = 0.f;
            int arg = 0;
            if (j < NTAG) {
                float va = -1e30f, vb = -1e30f, vc = -1e30f, vd = -1e30f;
                int ia = 0, ib = 13, ic = 26, id2 = 39;
                for (int i = 0; i < 13; i++) {
                    float s0 = st[i]      + Tm[i * NTAG + j];        if (s0 > va) { va = s0; ia = i; }
                    float s1 = st[i + 13] + Tm[(i + 13) * NTAG + j]; if (s1 > vb) { vb = s1; ib = i + 13; }
                    float s2 = st[i + 26] + Tm[(i + 26) * NTAG + j]; if (s2 > vc) { vc = s2; ic = i + 26; }
                    float s3 = st[i + 39] + Tm[(i + 39) * NTAG + j]; if (s3 > vd) { vd = s3; id2 = i + 39; }
                }
                float vm = va; arg = ia;
                if (vb > vm) { vm = vb; arg = ib; }
                if (vc > vm) { vm = vc; arg = ic; }
                if (vd > vm) { vm = vd; arg = id2; }
                vnew = vm + frow;
            }
            __builtin_amdgcn_wave_barrier();
            if (j < NTAG) {
                st[j] = vnew;
                bp[t - 1][j] = (unsigned char)arg;
            }
            __builtin_amdgcn_wave_barrier();
            frow = frow_nxt;
        }
        if (j == 0) {
            int best = 0;
            float vm = st[0] + Tm[0 * NTAG + TSTOP];
            for (int i = 1; i < NTAG; i++) {
                float v = st[i] + Tm[i * NTAG + TSTOP];
                if (v > vm) { vm = v; best = i; }
            }
            float* ot = outtags + (size_t)b * TT;
            int tag = best;
            ot[len - 1] = (float)tag;
            for (int t = len - 2; t >= 0; t--) {
                tag = bp[t][tag];
                ot[t] = (float)tag;
            }
            for (int t = len; t < TT; t++) ot[t] = 0.f;
        }
    }
}

extern "C" void kernel_launch(void* const* d_in, const int* in_sizes, int n_in,
                              void* d_out, int out_size, void* d_ws, size_t ws_size,
                              hipStream_t stream) {
    const int* batch_word     = (const int*)d_in[0];
    const int* batch_features = (const int*)d_in[1];
    const int* batch_wordlen  = (const int*)d_in[2];
    const int* batch_char     = (const int*)d_in[3];
    const int* batch_recover  = (const int*)d_in[5];
    const int* batch_label    = (const int*)d_in[7];
    const float* char_emb = (const float*)d_in[8];
    const float* conv_w   = (const float*)d_in[9];
    const float* conv_b   = (const float*)d_in[10];
    const float* word_emb = (const float*)d_in[11];
    const float* feat_emb = (const float*)d_in[12];
    const float* w_ih_f   = (const float*)d_in[13];
    const float* w_hh_f   = (const float*)d_in[14];
    const float* b_f      = (const float*)d_in[15];
    const float* w_ih_b   = (const float*)d_in[16];
    const float* w_hh_b   = (const float*)d_in[17];
    const float* b_b      = (const float*)d_in[18];
    const float* proj_w   = (const float*)d_in[19];
    const float* proj_b   = (const float*)d_in[20];
    const float* trans    = (const float*)d_in[21];

    char* ws = (char*)d_ws;
    float* pooled   = (float*)(ws + OFF_POOL);
    _Float16* xh    = (_Float16*)(ws + OFF_XH);
    _Float16* wh16f = (_Float16*)(ws + OFF_W16F);
    _Float16* wh16b = (_Float16*)(ws + OFF_W16B);
    _Float16* pw16  = (_Float16*)(ws + OFF_PW16);
    _Float16* hcat  = (_Float16*)(ws + OFF_HCAT);
    float* xs_f   = (float*)(ws + OFF_XSF);
    float* xs_b   = (float*)(ws + OFF_XSB);
    float* feats  = (float*)(ws + OFF_FEATS);
    _Float16* wh_f = (_Float16*)(ws + OFF_WPF);
    _Float16* wh_b = (_Float16*)(ws + OFF_WPB);
    float* lossb  = (float*)(ws + OFF_LOSSB);
    unsigned* ctr = (unsigned*)(ws + OFF_CTR);

    k_front<<<CHARCNN_BLOCKS + PREP_BLOCKS, 256, 0, stream>>>(
        batch_char, char_emb, conv_w, conv_b, pooled,
        w_hh_f, w_hh_b, w_ih_f, w_ih_b, proj_w,
        wh_f, wh_b, wh16f, wh16b, pw16, ctr);
    k_concat<<<(BB * TT) / 8, 256, 0, stream>>>(batch_word, batch_features, batch_recover,
                                                word_emb, feat_emb, pooled, xh);
    k_gemm16b<<<dim3(G4 / 64, (BB * TT) / 128), 256, 0, stream>>>(xh, wh16f, wh16b,
                                                                  b_f, b_b, xs_f, xs_b);
    k_lstm<<<128, 1024, 0, stream>>>(xs_f, xs_b, wh_f, wh_b, batch_wordlen, hcat);
    k_projm<<<(BB * TT) / 64, 256, 0, stream>>>(hcat, pw16, proj_b, feats);
    k_crf<<<2 * BB, 64, 0, stream>>>(feats, trans, batch_wordlen, batch_label,
                                     lossb, (float*)d_out + 1, ctr, (float*)d_out);
}

// Round 19
// 1325.049 us; speedup vs baseline: 1.4432x; 1.0295x over previous
//
#include <hip/hip_runtime.h>
#include <hip/hip_bf16.h>
#include <math.h>

#define BB 64
#define TT 256
#define LCH 16
#define DC 50
#define CHN 100
#define DW 300
#define DF 20
#define HID 256
#define G4 1024
#define INDIM 420
#define KPAD 448
#define NTAG 52
#define TSTART 50
#define TSTOP 51

// ------------------- workspace layout (bytes) -------------------
static constexpr size_t OFF_POOL  = 0;                       // 6,553,600 (dead after concat)
static constexpr size_t OFF_XH    = 6553600;                 // 14,680,064 f16 -> 21,233,664 (dead after gemm)
static constexpr size_t OFF_W16F  = 21233664;                // 917,504 f16 w_ih fwd
static constexpr size_t OFF_W16B  = 22151168;                // -> 23,068,672
static constexpr size_t OFF_PW16  = 23068672;                // 65,536 f16 proj_w -> 23,134,208
static constexpr size_t OFF_HCAT  = 0;                       // 16,777,216 f16 [16384][512] (lstm out)
static constexpr size_t OFF_XSF   = 34078720;                // 33,554,432 f16
static constexpr size_t OFF_XSB   = 101187584;               // 33,554,432 f16
static constexpr size_t OFF_FEATS = 168296448;               // 3,407,872 -> 171,704,320
static constexpr size_t OFF_WPF   = 171704320;               // 512 KB fp16 packed W_hh fwd
static constexpr size_t OFF_WPB   = 172752896;               // 512 KB fp16 packed W_hh bwd
static constexpr size_t OFF_LOSSB = 173801472;               // 256 B (64 floats)
static constexpr size_t OFF_CTR   = 173801728;               // 4 B (unsigned counter)

typedef _Float16 v2h __attribute__((ext_vector_type(2)));
typedef _Float16 f16x8 __attribute__((ext_vector_type(8)));
typedef float f32x4 __attribute__((ext_vector_type(4)));
union UH2 { unsigned u; v2h h; };
__device__ __forceinline__ float fdot2u(unsigned a, unsigned b, float c) {
    UH2 x, y; x.u = a; y.u = b;
    return __builtin_amdgcn_fdot2(x.h, y.h, c, false);
}
__device__ __forceinline__ float dot8(uint4 w, uint4 h, float acc) {
    acc = fdot2u(w.x, h.x, acc);
    acc = fdot2u(w.y, h.y, acc);
    acc = fdot2u(w.z, h.z, acc);
    acc = fdot2u(w.w, h.w, acc);
    return acc;
}
#define KEEPU4(v) asm volatile("" : "+v"((v).x), "+v"((v).y), "+v"((v).z), "+v"((v).w))

__device__ __forceinline__ float sigm(float x) { return 1.0f / (1.0f + expf(-x)); }

// ================= fused front kernel: charcnn (blocks 0..2047) +
//       prep pack/cvt incl. proj_w f16 (blocks 2048..) + counter zero ==========
#define CHARCNN_BLOCKS 2048
#define PREP_BLOCKS 5760          // ceil(1474560 / 256)

__device__ __forceinline__ void packh_one(const float* __restrict__ w,
                                          _Float16* __restrict__ wph, int e) {
    int r  = e & 7;
    int j  = (e >> 3) & 255;
    int k8 = (e >> 11) & 7;
    int g  = (e >> 14) & 3;
    int s  = (e >> 16) & 3;
    wph[e] = (_Float16)w[(g * 256 + j) * HID + (s * 64 + k8 * 8 + r)];
}
__device__ __forceinline__ void cvtw_one(const float* __restrict__ w,
                                         _Float16* __restrict__ wh, int e) {
    int row = e / KPAD, k = e % KPAD;
    wh[e] = (k < INDIM) ? (_Float16)w[row * INDIM + k] : (_Float16)0.f;
}

__global__ __launch_bounds__(256) void k_front(const int* __restrict__ bchar,
                                               const float* __restrict__ cemb,
                                               const float* __restrict__ cw,
                                               const float* __restrict__ cb,
                                               float* __restrict__ pooled,
                                               const float* __restrict__ whf,
                                               const float* __restrict__ whb,
                                               const float* __restrict__ wihf,
                                               const float* __restrict__ wihb,
                                               const float* __restrict__ pw,
                                               _Float16* __restrict__ wpf,
                                               _Float16* __restrict__ wpb,
                                               _Float16* __restrict__ wh16f,
                                               _Float16* __restrict__ wh16b,
                                               _Float16* __restrict__ pw16,
                                               unsigned* __restrict__ ctr) {
    __shared__ float cwsh[150][100];   // [d*3+q][c], 60 KB
    __shared__ float ET[2][DC][20];
    __shared__ int ids[2][LCH];
    int tid = threadIdx.x;
    if (blockIdx.x >= CHARCNN_BLOCKS) {
        // ---- prep body ----
        int e = (blockIdx.x - CHARCNN_BLOCKS) * 256 + tid;
        if (e == 0) *ctr = 0u;                       // zero last-block counter
        if (e < 262144)                packh_one(whf, wpf, e);
        else if (e < 524288)           packh_one(whb, wpb, e - 262144);
        else if (e < 983040)           cvtw_one(wihf, wh16f, e - 524288);
        else if (e < 1441792)          cvtw_one(wihb, wh16b, e - 983040);
        else if (e < 1474560) {
            int p = e - 1441792;                     // [64][512] f16, rows >= 52 zero
            int row = p >> 9;
            pw16[p] = (row < NTAG) ? (_Float16)pw[row * 512 + (p & 511)] : (_Float16)0.f;
        }
        return;
    }
    // ---- charcnn body: 8 words/block; cwsh + ET gathers coalesced ----
    int wbase = blockIdx.x * 8;
    for (int i = tid; i < 15000; i += 256) {
        int c = i / 150, row = i % 150;
        cwsh[row][c] = cw[i];
    }
    int half = tid >> 7, c = tid & 127;
    float bcv = (c < CHN) ? cb[c] : 0.f;
    for (int g = 0; g < 8; g += 2) {
        __syncthreads();
        if (tid < 32) ids[tid >> 4][tid & 15] = bchar[(wbase + g + (tid >> 4)) * LCH + (tid & 15)];
        __syncthreads();
        // d-fastest decomposition: 50 consecutive lanes read one cemb row coalesced
        for (int s2 = tid; s2 < 2 * DC * 18; s2 += 256) {
            int w2 = s2 / 900, rem = s2 % 900;
            int l = rem / DC, d = rem % DC;
            float v = 0.f;
            if (l >= 1 && l <= 16) v = cemb[ids[w2][l - 1] * DC + d];
            ET[w2][d][l] = v;
        }
        __syncthreads();
        if (c < CHN) {
            float acc[16];
#pragma unroll
            for (int l = 0; l < 16; l++) acc[l] = 0.f;
            for (int d = 0; d < DC; d++) {
                float e[18];
                float4 t0 = *(const float4*)&ET[half][d][0];
                float4 t1 = *(const float4*)&ET[half][d][4];
                float4 t2 = *(const float4*)&ET[half][d][8];
                float4 t3 = *(const float4*)&ET[half][d][12];
                e[0]=t0.x; e[1]=t0.y; e[2]=t0.z; e[3]=t0.w;
                e[4]=t1.x; e[5]=t1.y; e[6]=t1.z; e[7]=t1.w;
                e[8]=t2.x; e[9]=t2.y; e[10]=t2.z; e[11]=t2.w;
                e[12]=t3.x; e[13]=t3.y; e[14]=t3.z; e[15]=t3.w;
                e[16]=ET[half][d][16]; e[17]=ET[half][d][17];
                float w0 = cwsh[d * 3 + 0][c];
                float w1 = cwsh[d * 3 + 1][c];
                float w2 = cwsh[d * 3 + 2][c];
#pragma unroll
                for (int l = 0; l < 16; l++)
                    acc[l] += w0 * e[l] + w1 * e[l + 1] + w2 * e[l + 2];
            }
            float m = acc[0];
#pragma unroll
            for (int l = 1; l < 16; l++) m = fmaxf(m, acc[l]);
            pooled[(wbase + g + half) * CHN + c] = m + bcv;
        }
    }
}

// ---- assemble xh[16384][448] f16; 8 words per block, 256 threads
__global__ __launch_bounds__(256) void k_concat(const int* __restrict__ word,
                                                const int* __restrict__ featsidx,
                                                const int* __restrict__ recover,
                                                const float* __restrict__ wemb,
                                                const float* __restrict__ femb,
                                                const float* __restrict__ pooled,
                                                _Float16* __restrict__ xh) {
    int tid = threadIdx.x;
    for (int wi = 0; wi < 8; wi++) {
        int w = blockIdx.x * 8 + wi;
        int b = w >> 8;
        int wid = word[w];
        _Float16* xr = xh + (size_t)w * KPAD;
        if (tid < 150) {                               // DW=300 as 150 float2
            float2 v = ((const float2*)&wemb[(size_t)wid * DW])[tid];
            xr[2 * tid]     = (_Float16)v.x;
            xr[2 * tid + 1] = (_Float16)v.y;
        }
        int rc = recover[w];
        if (tid < CHN) xr[DW + tid] = (_Float16)pooled[rc * CHN + tid];
        if (tid < DF)  xr[DW + CHN + tid] = (_Float16)femb[featsidx[b] * DF + tid];
        if (tid >= 100 && tid < 100 + (KPAD - INDIM)) xr[INDIM + (tid - 100)] = (_Float16)0.f;
    }
}

// ---- fused f16 MFMA GEMM for BOTH directions, LDS-staged, reg-prefetched.
// C stored f16 (halves HBM write + LSTM read traffic).
__global__ __launch_bounds__(256, 4) void k_gemm16b(const _Float16* __restrict__ A,
                                                    const _Float16* __restrict__ Bf,
                                                    const _Float16* __restrict__ Bb,
                                                    const float* __restrict__ biasf,
                                                    const float* __restrict__ biasb,
                                                    _Float16* __restrict__ Cf,
                                                    _Float16* __restrict__ Cb) {
    __shared__ __align__(16) _Float16 Asl[128 * 72];
    __shared__ __align__(16) _Float16 Bfl[64 * 72];
    __shared__ __align__(16) _Float16 Bbl[64 * 72];
    int tid = threadIdx.x;
    int wv = tid >> 6, l = tid & 63;
    int lm = l & 15, lk = l >> 4;
    int n0 = blockIdx.x * 64, m0 = blockIdx.y * 128;
    f32x4 z = {0.f, 0.f, 0.f, 0.f};
    f32x4 af0 = z, af1 = z, af2 = z, af3 = z;
    f32x4 ag0 = z, ag1 = z, ag2 = z, ag3 = z;
    f32x4 ab0 = z, ab1 = z, ab2 = z, ab3 = z;
    f32x4 ac0 = z, ac1 = z, ac2 = z, ac3 = z;
    int ra_[4], rca_[4];
#pragma unroll
    for (int q = 0; q < 4; q++) { int ch = tid + q * 256; ra_[q] = ch >> 3; rca_[q] = ch & 7; }
    int rb_[2], rcb_[2];
#pragma unroll
    for (int q = 0; q < 2; q++) { int ch = tid + q * 256; rb_[q] = ch >> 3; rcb_[q] = ch & 7; }
    for (int k0 = 0; k0 < KPAD; k0 += 64) {
        uint4 va[4], vbf[2], vbb[2];
#pragma unroll
        for (int q = 0; q < 4; q++)
            va[q] = *(const uint4*)&A[(size_t)(m0 + ra_[q]) * KPAD + k0 + rca_[q] * 8];
#pragma unroll
        for (int q = 0; q < 2; q++) {
            vbf[q] = *(const uint4*)&Bf[(size_t)(n0 + rb_[q]) * KPAD + k0 + rcb_[q] * 8];
            vbb[q] = *(const uint4*)&Bb[(size_t)(n0 + rb_[q]) * KPAD + k0 + rcb_[q] * 8];
        }
        __syncthreads();
#pragma unroll
        for (int q = 0; q < 4; q++)
            ((uint4*)Asl)[ra_[q] * 9 + rca_[q]] = va[q];
#pragma unroll
        for (int q = 0; q < 2; q++) {
            ((uint4*)Bfl)[rb_[q] * 9 + rcb_[q]] = vbf[q];
            ((uint4*)Bbl)[rb_[q] * 9 + rcb_[q]] = vbb[q];
        }
        __syncthreads();
#pragma unroll
        for (int kstep = 0; kstep < 2; kstep++) {
            int kk = kstep * 4 + lk;
            f16x8 a0 = ((const f16x8*)Asl)[(wv * 32 + lm) * 9 + kk];
            f16x8 a1 = ((const f16x8*)Asl)[(wv * 32 + 16 + lm) * 9 + kk];
            f16x8 b0 = ((const f16x8*)Bfl)[(0 * 16 + lm) * 9 + kk];
            f16x8 b1 = ((const f16x8*)Bfl)[(1 * 16 + lm) * 9 + kk];
            f16x8 b2 = ((const f16x8*)Bfl)[(2 * 16 + lm) * 9 + kk];
            f16x8 b3 = ((const f16x8*)Bfl)[(3 * 16 + lm) * 9 + kk];
            f16x8 c0 = ((const f16x8*)Bbl)[(0 * 16 + lm) * 9 + kk];
            f16x8 c1 = ((const f16x8*)Bbl)[(1 * 16 + lm) * 9 + kk];
            f16x8 c2 = ((const f16x8*)Bbl)[(2 * 16 + lm) * 9 + kk];
            f16x8 c3 = ((const f16x8*)Bbl)[(3 * 16 + lm) * 9 + kk];
            af0 = __builtin_amdgcn_mfma_f32_16x16x32_f16(a0, b0, af0, 0, 0, 0);
            af1 = __builtin_amdgcn_mfma_f32_16x16x32_f16(a0, b1, af1, 0, 0, 0);
            af2 = __builtin_amdgcn_mfma_f32_16x16x32_f16(a0, b2, af2, 0, 0, 0);
            af3 = __builtin_amdgcn_mfma_f32_16x16x32_f16(a0, b3, af3, 0, 0, 0);
            ag0 = __builtin_amdgcn_mfma_f32_16x16x32_f16(a1, b0, ag0, 0, 0, 0);
            ag1 = __builtin_amdgcn_mfma_f32_16x16x32_f16(a1, b1, ag1, 0, 0, 0);
            ag2 = __builtin_amdgcn_mfma_f32_16x16x32_f16(a1, b2, ag2, 0, 0, 0);
            ag3 = __builtin_amdgcn_mfma_f32_16x16x32_f16(a1, b3, ag3, 0, 0, 0);
            ab0 = __builtin_amdgcn_mfma_f32_16x16x32_f16(a0, c0, ab0, 0, 0, 0);
            ab1 = __builtin_amdgcn_mfma_f32_16x16x32_f16(a0, c1, ab1, 0, 0, 0);
            ab2 = __builtin_amdgcn_mfma_f32_16x16x32_f16(a0, c2, ab2, 0, 0, 0);
            ab3 = __builtin_amdgcn_mfma_f32_16x16x32_f16(a0, c3, ab3, 0, 0, 0);
            ac0 = __builtin_amdgcn_mfma_f32_16x16x32_f16(a1, c0, ac0, 0, 0, 0);
            ac1 = __builtin_amdgcn_mfma_f32_16x16x32_f16(a1, c1, ac1, 0, 0, 0);
            ac2 = __builtin_amdgcn_mfma_f32_16x16x32_f16(a1, c2, ac2, 0, 0, 0);
            ac3 = __builtin_amdgcn_mfma_f32_16x16x32_f16(a1, c3, ac3, 0, 0, 0);
        }
    }
    f32x4 fa[2][4] = {{af0, af1, af2, af3}, {ag0, ag1, ag2, ag3}};
    f32x4 ba[2][4] = {{ab0, ab1, ab2, ab3}, {ac0, ac1, ac2, ac3}};
#pragma unroll
    for (int mi = 0; mi < 2; mi++) {
        int orow = m0 + wv * 32 + mi * 16 + lk * 4;
#pragma unroll
        for (int jn = 0; jn < 4; jn++) {
            int col = n0 + jn * 16 + lm;
            float bvf = biasf[col], bvb = biasb[col];
#pragma unroll
            for (int r = 0; r < 4; r++) {
                Cf[(size_t)(orow + r) * G4 + col] = (_Float16)(fa[mi][jn][r] + bvf);
                Cb[(size_t)(orow + r) * G4 + col] = (_Float16)(ba[mi][jn][r] + bvb);
            }
        }
    }
}

// ---- masked BiLSTM (r13 structure): o-gate in 128 KB LDS; g-gate in 32 VGPRs;
// i,f streamed 256 KB/step from L2. x inputs f16; h stored f16 into hcat.
__global__ __launch_bounds__(1024, 4) void k_lstm(const _Float16* __restrict__ xs_f,
                                               const _Float16* __restrict__ xs_b,
                                               const _Float16* __restrict__ wh_f,
                                               const _Float16* __restrict__ wh_b,
                                               const int* __restrict__ wlen,
                                               _Float16* __restrict__ hcat) {
    int b = blockIdx.x & 63, d = blockIdx.x >> 6;
    const _Float16* xs = d ? xs_b : xs_f;
    const uint4* wp4 = (const uint4*)(d ? wh_b : wh_f);
    int len = wlen[b];
    __shared__ uint4 olds4[8192];                 // o-gate weights, 128 KB
    __shared__ _Float16 __align__(16) hh[256];    // f16 h state
    __shared__ float part[4][4][256];             // [s][gate][unit], 16 KB
    int tid = threadIdx.x;
    int j = tid & 255, s = tid >> 8;
    const uint4* pi = wp4 + (size_t)((s * 4 + 0) * 8) * 256 + j;   // i (streamed)
    const uint4* pf = wp4 + (size_t)((s * 4 + 1) * 8) * 256 + j;   // f (streamed)
    uint4 wg[8];                                   // g-gate resident (32 VGPRs)
    {
        const uint4* pg = wp4 + (size_t)((s * 4 + 2) * 8) * 256 + j;
        const uint4* po = wp4 + (size_t)((s * 4 + 3) * 8) * 256 + j;
#pragma unroll
        for (int k8 = 0; k8 < 8; k8++) {
            wg[k8] = pg[k8 * 256];
            olds4[k8 * 1024 + tid] = po[k8 * 256];
        }
    }
#pragma unroll
    for (int k8 = 0; k8 < 8; k8++) KEEPU4(wg[k8]);
    if (tid < 128) ((unsigned*)hh)[tid] = 0u;
    float c = 0.f;
    const uint4* hsh4 = (const uint4*)hh;
    __syncthreads();
    for (int ss = 0; ss < len; ++ss) {
        int t = d ? (len - 1 - ss) : ss;
        float xv0, xv1, xv2, xv3;
        if (tid < 256) {
            const _Float16* xr = xs + (size_t)(b * TT + t) * G4;
            xv0 = (float)xr[tid];
            xv1 = (float)xr[256 + tid];
            xv2 = (float)xr[512 + tid];
            xv3 = (float)xr[768 + tid];
        }
        asm volatile("" : "+v"(pi), "+v"(pf));
        float a0 = 0.f, a1 = 0.f, a2 = 0.f, a3 = 0.f;
#pragma unroll
        for (int k8 = 0; k8 < 8; k8++) {
            uint4 h4 = hsh4[s * 8 + k8];                       // broadcast
            uint4 wi = pi[k8 * 256];
            uint4 wf = pf[k8 * 256];
            uint4 wo = olds4[k8 * 1024 + tid];
            a0 = dot8(wi, h4, a0);
            a1 = dot8(wf, h4, a1);
            a2 = dot8(wg[k8], h4, a2);
            a3 = dot8(wo, h4, a3);
        }
        part[s][0][j] = a0;
        part[s][1][j] = a1;
        part[s][2][j] = a2;
        part[s][3][j] = a3;
        __syncthreads();
        if (tid < 256) {
            float s0 = part[0][0][tid] + part[1][0][tid] + part[2][0][tid] + part[3][0][tid] + xv0;
            float s1 = part[0][1][tid] + part[1][1][tid] + part[2][1][tid] + part[3][1][tid] + xv1;
            float s2 = part[0][2][tid] + part[1][2][tid] + part[2][2][tid] + part[3][2][tid] + xv2;
            float s3 = part[0][3][tid] + part[1][3][tid] + part[2][3][tid] + part[3][3][tid] + xv3;
            float ig = sigm(s0), fg = sigm(s1), zg = tanhf(s2), og = sigm(s3);
            c = fg * c + ig * zg;
            float h = og * tanhf(c);
            _Float16 h16 = (_Float16)h;
            hh[tid] = h16;
            hcat[(size_t)(b * TT + t) * 512 + d * 256 + tid] = h16;
        }
        __syncthreads();
    }
}

// ---- projection via MFMA: feats[w][52] = hcat[w][0:512] . pw16[tag][0:512] + pb
__global__ __launch_bounds__(256) void k_projm(const _Float16* __restrict__ A,
                                               const _Float16* __restrict__ Bw,
                                               const float* __restrict__ pb,
                                               float* __restrict__ feats) {
    __shared__ __align__(16) _Float16 Al[8 * 64 * 72];
    __shared__ __align__(16) _Float16 Bl[8 * 64 * 72];
    int tid = threadIdx.x;
    int wv = tid >> 6, l = tid & 63;
    int lm = l & 15, lk = l >> 4;
    int m0 = blockIdx.x * 64;
#pragma unroll
    for (int q = 0; q < 16; q++) {
        int ch = tid + q * 256;           // 0..4095 uint4
        int r = ch >> 6;                  // row 0..63
        int rem = ch & 63;
        int cnk = rem >> 3, cc = rem & 7;
        ((uint4*)Al)[(cnk * 64 + r) * 9 + cc] =
            *(const uint4*)&A[(size_t)(m0 + r) * 512 + cnk * 64 + cc * 8];
        ((uint4*)Bl)[(cnk * 64 + r) * 9 + cc] =
            *(const uint4*)&Bw[(size_t)r * 512 + cnk * 64 + cc * 8];
    }
    __syncthreads();
    f32x4 z = {0.f, 0.f, 0.f, 0.f};
    f32x4 ac0 = z, ac1 = z, ac2 = z, ac3 = z;
#pragma unroll
    for (int cnk = 0; cnk < 8; cnk++) {
#pragma unroll
        for (int ks = 0; ks < 2; ks++) {
            int kk = ks * 4 + lk;
            f16x8 a  = ((const f16x8*)Al)[(cnk * 64 + wv * 16 + lm) * 9 + kk];
            f16x8 b0 = ((const f16x8*)Bl)[(cnk * 64 +  0 + lm) * 9 + kk];
            f16x8 b1 = ((const f16x8*)Bl)[(cnk * 64 + 16 + lm) * 9 + kk];
            f16x8 b2 = ((const f16x8*)Bl)[(cnk * 64 + 32 + lm) * 9 + kk];
            f16x8 b3 = ((const f16x8*)Bl)[(cnk * 64 + 48 + lm) * 9 + kk];
            ac0 = __builtin_amdgcn_mfma_f32_16x16x32_f16(a, b0, ac0, 0, 0, 0);
            ac1 = __builtin_amdgcn_mfma_f32_16x16x32_f16(a, b1, ac1, 0, 0, 0);
            ac2 = __builtin_amdgcn_mfma_f32_16x16x32_f16(a, b2, ac2, 0, 0, 0);
            ac3 = __builtin_amdgcn_mfma_f32_16x16x32_f16(a, b3, ac3, 0, 0, 0);
        }
    }
    f32x4 accs[4] = {ac0, ac1, ac2, ac3};
    int orow = m0 + wv * 16 + lk * 4;
#pragma unroll
    for (int jn = 0; jn < 4; jn++) {
        int col = jn * 16 + lm;
        if (col < NTAG) {
            float bv = pb[col];
#pragma unroll
            for (int r = 0; r < 4; r++)
                feats[(size_t)(orow + r) * NTAG + col] = accs[jn][r] + bv;
        }
    }
}

// ---- CRF: 128 single-wave blocks; v_ij cached in registers (computed once).
__global__ __launch_bounds__(64) void k_crf(const float* __restrict__ feats,
                                            const float* __restrict__ trans,
                                            const int* __restrict__ wlen,
                                            const int* __restrict__ blabel,
                                            float* __restrict__ lossb,
                                            float* __restrict__ outtags,
                                            unsigned* __restrict__ ctr,
                                            float* __restrict__ out) {
    __shared__ float Tm[NTAG * NTAG];
    __shared__ float st[NTAG];
    __shared__ unsigned char bp[TT - 1][NTAG];
    int bid = blockIdx.x;
    int b = bid & 63;
    bool vit = bid >= BB;
    int j = threadIdx.x;
    for (int s = j; s < NTAG * NTAG; s += 64) Tm[s] = trans[s];
    __builtin_amdgcn_wave_barrier();
    int len = wlen[b];
    const float* fb = feats + (size_t)b * TT * NTAG;
    if (j < NTAG) st[j] = fb[j] + Tm[TSTART * NTAG + j];
    __builtin_amdgcn_wave_barrier();
    if (!vit) {
        float frow = (j < NTAG && len > 1) ? fb[NTAG + j] : 0.f;
        for (int t = 1; t < len; t++) {
            float frow_nxt = (j < NTAG && t + 1 < len) ? fb[(size_t)(t + 1) * NTAG + j] : 0.f;
            float anew = 0.f;
            if (j < NTAG) {
                float v0[13], v1[13], v2[13], v3[13];
                float ma = -1e30f, mb = -1e30f, mc = -1e30f, md = -1e30f;
#pragma unroll
                for (int i = 0; i < 13; i++) {
                    v0[i] = st[i]      + Tm[i * NTAG + j];
                    v1[i] = st[i + 13] + Tm[(i + 13) * NTAG + j];
                    v2[i] = st[i + 26] + Tm[(i + 26) * NTAG + j];
                    v3[i] = st[i + 39] + Tm[(i + 39) * NTAG + j];
                    ma = fmaxf(ma, v0[i]);
                    mb = fmaxf(mb, v1[i]);
                    mc = fmaxf(mc, v2[i]);
                    md = fmaxf(md, v3[i]);
                }
                float m1 = fmaxf(fmaxf(ma, mb), fmaxf(mc, md));
                float sa = 0.f, sb = 0.f, sc = 0.f, sd = 0.f;
#pragma unroll
                for (int i = 0; i < 13; i++) {
                    sa += __expf(v0[i] - m1);
                    sb += __expf(v1[i] - m1);
                    sc += __expf(v2[i] - m1);
                    sd += __expf(v3[i] - m1);
                }
                anew = m1 + __logf((sa + sb) + (sc + sd)) + frow;
            }
            __builtin_amdgcn_wave_barrier();
            if (j < NTAG) st[j] = anew;
            __builtin_amdgcn_wave_barrier();
            frow = frow_nxt;
        }
        float red = (j < NTAG) ? st[j] + Tm[j * NTAG + TSTOP] : -1e30f;
        float m1 = red;
#pragma unroll
        for (int m = 32; m; m >>= 1) m1 = fmaxf(m1, __shfl_xor(m1, m));
        float e = (j < NTAG) ? __expf(red - m1) : 0.f;
        float ssum = e;
#pragma unroll
        for (int m = 32; m; m >>= 1) ssum += __shfl_xor(ssum, m);
        const int* lab = blabel + b * TT;
        float gpart = 0.f;
        for (int t = 1 + j; t < len; t += 64)
            gpart += Tm[lab[t - 1] * NTAG + lab[t]] + fb[(size_t)t * NTAG + lab[t]];
#pragma unroll
        for (int m = 32; m; m >>= 1) gpart += __shfl_xor(gpart, m);
        if (j == 0) {
            float Zg = m1 + __logf(ssum);
            float goldv = Tm[TSTART * NTAG + lab[0]] + fb[lab[0]] + gpart
                        + Tm[lab[len - 1] * NTAG + TSTOP];
            lossb[b] = Zg - goldv;
            __threadfence();
            unsigned old = atomicAdd(ctr, 1u);
            if (old == BB - 1) {
                __threadfence();
                float stot = 0.f;
                for (int i = 0; i < BB; i++) stot += lossb[i];
                out[0] = stot;
            }
        }
    } else {
        float frow = (j < NTAG && len > 1) ? fb[NTAG + j] : 0.f;
        for (int t = 1; t < len; t++) {
            float frow_nxt = (j < NTAG && t + 1 < len) ? fb[(size_t)(t + 1) * NTAG + j] : 0.f;
            float vnew = 0.f;
            int arg = 0;
            if (j < NTAG) {
                float v0[13], v1[13], v2[13], v3[13];
#pragma unroll
                for (int i = 0; i < 13; i++) {
                    v0[i] = st[i]      + Tm[i * NTAG + j];
                    v1[i] = st[i + 13] + Tm[(i + 13) * NTAG + j];
                    v2[i] = st[i + 26] + Tm[(i + 26) * NTAG + j];
                    v3[i] = st[i + 39] + Tm[(i + 39) * NTAG + j];
                }
                float va = -1e30f, vb = -1e30f, vc = -1e30f, vd = -1e30f;
                int ia = 0, ib = 13, ic = 26, id2 = 39;
#pragma unroll
                for (int i = 0; i < 13; i++) {
                    if (v0[i] > va) { va = v0[i]; ia = i; }
                    if (v1[i] > vb) { vb = v1[i]; ib = i + 13; }
                    if (v2[i] > vc) { vc = v2[i]; ic = i + 26; }
                    if (v3[i] > vd) { vd = v3[i]; id2 = i + 39; }
                }
                float vm = va; arg = ia;
                if (vb > vm) { vm = vb; arg = ib; }
                if (vc > vm) { vm = vc; arg = ic; }
                if (vd > vm) { vm = vd; arg = id2; }
                vnew = vm + frow;
            }
            __builtin_amdgcn_wave_barrier();
            if (j < NTAG) {
                st[j] = vnew;
                bp[t - 1][j] = (unsigned char)arg;
            }
            __builtin_amdgcn_wave_barrier();
            frow = frow_nxt;
        }
        if (j == 0) {
            int best = 0;
            float vm = st[0] + Tm[0 * NTAG + TSTOP];
            for (int i = 1; i < NTAG; i++) {
                float v = st[i] + Tm[i * NTAG + TSTOP];
                if (v > vm) { vm = v; best = i; }
            }
            float* ot = outtags + (size_t)b * TT;
            int tag = best;
            ot[len - 1] = (float)tag;
            for (int t = len - 2; t >= 0; t--) {
                tag = bp[t][tag];
                ot[t] = (float)tag;
            }
            for (int t = len; t < TT; t++) ot[t] = 0.f;
        }
    }
}

extern "C" void kernel_launch(void* const* d_in, const int* in_sizes, int n_in,
                              void* d_out, int out_size, void* d_ws, size_t ws_size,
                              hipStream_t stream) {
    const int* batch_word     = (const int*)d_in[0];
    const int* batch_features = (const int*)d_in[1];
    const int* batch_wordlen  = (const int*)d_in[2];
    const int* batch_char     = (const int*)d_in[3];
    const int* batch_recover  = (const int*)d_in[5];
    const int* batch_label    = (const int*)d_in[7];
    const float* char_emb = (const float*)d_in[8];
    const float* conv_w   = (const float*)d_in[9];
    const float* conv_b   = (const float*)d_in[10];
    const float* word_emb = (const float*)d_in[11];
    const float* feat_emb = (const float*)d_in[12];
    const float* w_ih_f   = (const float*)d_in[13];
    const float* w_hh_f   = (const float*)d_in[14];
    const float* b_f      = (const float*)d_in[15];
    const float* w_ih_b   = (const float*)d_in[16];
    const float* w_hh_b   = (const float*)d_in[17];
    const float* b_b      = (const float*)d_in[18];
    const float* proj_w   = (const float*)d_in[19];
    const float* proj_b   = (const float*)d_in[20];
    const float* trans    = (const float*)d_in[21];

    char* ws = (char*)d_ws;
    float* pooled   = (float*)(ws + OFF_POOL);
    _Float16* xh    = (_Float16*)(ws + OFF_XH);
    _Float16* wh16f = (_Float16*)(ws + OFF_W16F);
    _Float16* wh16b = (_Float16*)(ws + OFF_W16B);
    _Float16* pw16  = (_Float16*)(ws + OFF_PW16);
    _Float16* hcat  = (_Float16*)(ws + OFF_HCAT);
    _Float16* xs_f  = (_Float16*)(ws + OFF_XSF);
    _Float16* xs_b  = (_Float16*)(ws + OFF_XSB);
    float* feats  = (float*)(ws + OFF_FEATS);
    _Float16* wh_f = (_Float16*)(ws + OFF_WPF);
    _Float16* wh_b = (_Float16*)(ws + OFF_WPB);
    float* lossb  = (float*)(ws + OFF_LOSSB);
    unsigned* ctr = (unsigned*)(ws + OFF_CTR);

    k_front<<<CHARCNN_BLOCKS + PREP_BLOCKS, 256, 0, stream>>>(
        batch_char, char_emb, conv_w, conv_b, pooled,
        w_hh_f, w_hh_b, w_ih_f, w_ih_b, proj_w,
        wh_f, wh_b, wh16f, wh16b, pw16, ctr);
    k_concat<<<(BB * TT) / 8, 256, 0, stream>>>(batch_word, batch_features, batch_recover,
                                                word_emb, feat_emb, pooled, xh);
    k_gemm16b<<<dim3(G4 / 64, (BB * TT) / 128), 256, 0, stream>>>(xh, wh16f, wh16b,
                                                                  b_f, b_b, xs_f, xs_b);
    k_lstm<<<128, 1024, 0, stream>>>(xs_f, xs_b, wh_f, wh_b, batch_wordlen, hcat);
    k_projm<<<(BB * TT) / 64, 256, 0, stream>>>(hcat, pw16, proj_b, feats);
    k_crf<<<2 * BB, 64, 0, stream>>>(feats, trans, batch_wordlen, batch_label,
                                     lossb, (float*)d_out + 1, ctr, (float*)d_out);
}